// Round 7
// baseline (1008.319 us; speedup 1.0000x reference)
//
#include <hip/hip_runtime.h>
#include <hip/hip_bf16.h>
#include <hip/hip_fp16.h>

#define NN 50000
#define NE 800000
#define FIN 128
#define HCC 256   // HEADS*HID
#define OC 64
#define NSL 0.2f
#define NT3 (3 * NN)

typedef __attribute__((ext_vector_type(8))) short sh8;
typedef __attribute__((ext_vector_type(16))) float f32x16;

struct __attribute__((aligned(8))) h4 { __half x, y, z, w; };
struct __attribute__((aligned(8))) s4 { short x, y, z, w; };

__device__ __forceinline__ unsigned short bf_rne(float f) {
  unsigned u = __float_as_uint(f);
  u += 0x7FFF + ((u >> 16) & 1);
  return (unsigned short)(u >> 16);
}

__device__ __forceinline__ float edge_w(float lg) {
  lg = (lg > 0.f) ? lg : NSL * lg;
  return __expf(lg);
}

// -------- weight pre-split into chunked-coalesced layout --------
// W:[3][KK][256] fp32 -> out:[3][cb(2)][hl(2)][KK/8][c(128)][8] bf16
template<int KK>
__global__ __launch_bounds__(256) void k_prep(const float* __restrict__ W,
                                              short* __restrict__ out) {
  int i = blockIdx.x * 256 + threadIdx.x;
  if (i >= 3 * KK * 256) return;
  int r = i / (KK * 256);
  int rem = i - r * KK * 256;
  int k = rem >> 8;
  int n = rem & 255;
  float f = W[i];
  unsigned short hb = bf_rne(f);
  float hf = __uint_as_float(((unsigned)hb) << 16);
  unsigned short lb = bf_rne(f - hf);
  int cb = n >> 7, c = n & 127, ks8 = k >> 3, kj = k & 7;
  size_t base = (size_t)r * 4 * KK * 128;
  size_t oh = base + ((size_t)((cb * 2 + 0) * (KK / 8) + ks8) * 128 + c) * 8 + kj;
  size_t ol = base + ((size_t)((cb * 2 + 1) * (KK / 8) + ks8) * 128 + c) * 8 + kj;
  out[oh] = (short)hb;
  out[ol] = (short)lb;
}

// -------- x fp32 -> bf16 hi/lo --------
__global__ __launch_bounds__(256) void k_split(const float* __restrict__ x,
                                               short* __restrict__ xhi,
                                               short* __restrict__ xlo) {
  int i = blockIdx.x * 256 + threadIdx.x;
  if (i >= NN * FIN / 4) return;
  float4 v = ((const float4*)x)[i];
  s4 h, l;
  float f, hf;
  f = v.x; h.x = (short)bf_rne(f); hf = __uint_as_float(((unsigned)(unsigned short)h.x) << 16); l.x = (short)bf_rne(f - hf);
  f = v.y; h.y = (short)bf_rne(f); hf = __uint_as_float(((unsigned)(unsigned short)h.y) << 16); l.y = (short)bf_rne(f - hf);
  f = v.z; h.z = (short)bf_rne(f); hf = __uint_as_float(((unsigned)(unsigned short)h.z) << 16); l.z = (short)bf_rne(f - hf);
  f = v.w; h.w = (short)bf_rne(f); hf = __uint_as_float(((unsigned)(unsigned short)h.w) << 16); l.w = (short)bf_rne(f - hf);
  ((s4*)xhi)[i] = h;
  ((s4*)xlo)[i] = l;
}

// ---------------- CSR build ----------------
__global__ void k_hist3(const int* __restrict__ e0, const int* __restrict__ e1,
                        const int* __restrict__ e2, int* __restrict__ deg3) {
  int i = blockIdx.x * blockDim.x + threadIdx.x;
  int st = gridDim.x * blockDim.x;
  for (; i < 3 * NE; i += st) {
    int rel = i / NE;
    int j = i - rel * NE;
    const int* e = (rel == 0) ? e0 : ((rel == 1) ? e1 : e2);
    atomicAdd(&deg3[rel * NN + e[NE + j]], 1);
  }
}

__global__ __launch_bounds__(1024) void k_bsum(const int* __restrict__ deg3,
                                               int* __restrict__ bsum) {
  __shared__ int s[1024];
  int t = threadIdx.x;
  int i = blockIdx.x * 1024 + t;
  s[t] = (i < NT3) ? deg3[i] : 0;
  __syncthreads();
  for (int off = 512; off > 0; off >>= 1) {
    if (t < off) s[t] += s[t + off];
    __syncthreads();
  }
  if (t == 0) bsum[blockIdx.x] = s[0];
}

__global__ __launch_bounds__(256) void k_scan2(const int* __restrict__ bsum,
                                               int* __restrict__ boffs, int nb) {
  __shared__ int s[256];
  int t = threadIdx.x;
  int v = (t < nb) ? bsum[t] : 0;
  s[t] = v;
  __syncthreads();
  for (int off = 1; off < 256; off <<= 1) {
    int x = (t >= off) ? s[t - off] : 0;
    __syncthreads();
    s[t] += x;
    __syncthreads();
  }
  if (t < nb) boffs[t] = s[t] - v;  // exclusive
}

__global__ __launch_bounds__(1024) void k_rowptr(const int* __restrict__ deg3,
                                                 const int* __restrict__ boffs,
                                                 int* __restrict__ rpA,
                                                 int* __restrict__ cursor3) {
  __shared__ int s[1024];
  int t = threadIdx.x;
  int i = blockIdx.x * 1024 + t;
  int d = (i < NT3) ? deg3[i] : 0;
  s[t] = d;
  __syncthreads();
  for (int off = 1; off < 1024; off <<= 1) {
    int x = (t >= off) ? s[t - off] : 0;
    __syncthreads();
    s[t] += x;
    __syncthreads();
  }
  if (i < NT3) {
    int excl = boffs[blockIdx.x] + s[t] - d;
    int r = (i < NN) ? 0 : ((i < 2 * NN) ? 1 : 2);
    int n = i - r * NN;
    int val = excl - r * NE;
    rpA[r * (NN + 1) + n] = val;
    cursor3[i] = val;
  }
  if (blockIdx.x == 0 && t < 3) rpA[t * (NN + 1) + NN] = NE;
}

__global__ void k_scatter3(const int* __restrict__ e0, const int* __restrict__ e1,
                           const int* __restrict__ e2, int* __restrict__ cursor3,
                           int* __restrict__ csAll) {
  int i = blockIdx.x * blockDim.x + threadIdx.x;
  int st = gridDim.x * blockDim.x;
  for (; i < 3 * NE; i += st) {
    int rel = i / NE;
    int j = i - rel * NE;
    const int* e = (rel == 0) ? e0 : ((rel == 1) ? e1 : e2);
    int pos = atomicAdd(&cursor3[rel * NN + e[NE + j]], 1);
    csAll[(size_t)rel * NE + pos] = e[j];
  }
}

// -------- split-bf16 MFMA GEMM (32x32x16), pre-split A, 3 relations, alpha fused ----
template<int KK>
__global__ __launch_bounds__(256) void k_mgemm(const short* __restrict__ Ahi,
                                               const short* __restrict__ Alo,
                                               const short* __restrict__ BcAll,
                                               const float* __restrict__ asfAll,
                                               const float* __restrict__ adfAll,
                                               __half* __restrict__ houtAll,
                                               float* __restrict__ alsAll,
                                               float* __restrict__ aldAll, int M) {
  const int rel = blockIdx.y;
  const short* Bc = BcAll + (size_t)rel * 4 * KK * 128;
  const float* asf = asfAll + rel * HCC;
  const float* adf = adfAll + rel * HCC;
  __half* hout = houtAll + (size_t)rel * NN * HCC;
  float* als = alsAll + (size_t)rel * NN * 4;
  float* ald = aldAll + (size_t)rel * NN * 4;

  const int tid = threadIdx.x;
  const int lane = tid & 63;
  const int w = tid >> 6;
  const int l31 = lane & 31;
  const int lg = lane >> 5;
  const int wrow = blockIdx.x * 64 + (w & 1) * 32;
  const int ch = w >> 1;

  f32x16 acc[4];
#pragma unroll
  for (int t = 0; t < 4; ++t) acc[t] = (f32x16)(0.f);

  const int r = wrow + l31;
  const bool aok = r < M;
  const short* ahp = Ahi + (size_t)r * KK;
  const short* alp = Alo + (size_t)r * KK;
  const short* bh = Bc + (size_t)(ch * 2 + 0) * KK * 128 + l31 * 8;
  const short* bl = Bc + (size_t)(ch * 2 + 1) * KK * 128 + l31 * 8;

#pragma unroll 2
  for (int kst = 0; kst < KK / 16; ++kst) {
    const int k0 = kst * 16 + lg * 8;
    sh8 ahi = {0, 0, 0, 0, 0, 0, 0, 0}, alo = ahi;
    if (aok) {
      ahi = *(const sh8*)(ahp + k0);
      alo = *(const sh8*)(alp + k0);
    }
    const int ks8 = kst * 2 + lg;
    const short* bhp = bh + (size_t)ks8 * 1024;
    const short* blp = bl + (size_t)ks8 * 1024;
    sh8 bhf[4], blf[4];
#pragma unroll
    for (int t = 0; t < 4; ++t) {
      bhf[t] = *(const sh8*)(bhp + t * 256);
      blf[t] = *(const sh8*)(blp + t * 256);
    }
#pragma unroll
    for (int t = 0; t < 4; ++t) {
      acc[t] = __builtin_amdgcn_mfma_f32_32x32x16_bf16(ahi, bhf[t], acc[t], 0, 0, 0);
      acc[t] = __builtin_amdgcn_mfma_f32_32x32x16_bf16(alo, bhf[t], acc[t], 0, 0, 0);
      acc[t] = __builtin_amdgcn_mfma_f32_32x32x16_bf16(ahi, blf[t], acc[t], 0, 0, 0);
    }
  }

  // epilogue: h (fp16) store + fused alpha (2 heads per col-half)
  float asr[4], adr[4];
#pragma unroll
  for (int t = 0; t < 4; ++t) {
    int col = ch * 128 + t * 32 + l31;
    asr[t] = asf[col];
    adr[t] = adf[col];
  }
#pragma unroll
  for (int v = 0; v < 16; ++v) {
    const int rl = (v & 3) + 8 * (v >> 2) + 4 * lg;
    const int row = wrow + rl;
    const bool rok = row < M;
    float s0 = 0.f, s1 = 0.f, d0 = 0.f, d1 = 0.f;
    __half* hp = hout + (size_t)row * 256 + ch * 128 + l31;
#pragma unroll
    for (int t = 0; t < 4; ++t) {
      float dv = acc[t][v];
      if (rok) hp[t * 32] = __float2half(dv);
      if (t < 2) { s0 += dv * asr[t]; d0 += dv * adr[t]; }
      else       { s1 += dv * asr[t]; d1 += dv * adr[t]; }
    }
#pragma unroll
    for (int m = 1; m < 32; m <<= 1) {
      s0 += __shfl_xor(s0, m);
      s1 += __shfl_xor(s1, m);
      d0 += __shfl_xor(d0, m);
      d1 += __shfl_xor(d1, m);
    }
    if (rok && l31 == 0) {
      *(float2*)(als + (size_t)row * 4 + ch * 2) = make_float2(s0, s1);
      *(float2*)(ald + (size_t)row * 4 + ch * 2) = make_float2(d0, d1);
    }
  }
}

// -------- edge weights: one wave per (rel, node); ew[pos][head], wsum, self --------
__global__ __launch_bounds__(256) void k_ew3(const float* __restrict__ als3,
                                             const float* __restrict__ ald3,
                                             const int* __restrict__ rpA,
                                             const int* __restrict__ csAll,
                                             float* __restrict__ ew3,
                                             float* __restrict__ wsum3,
                                             float* __restrict__ ewself3) {
  int wid = (blockIdx.x * 256 + threadIdx.x) >> 6;
  int lane = threadIdx.x & 63;
  if (wid >= NT3) return;
  int rel = wid / NN;
  int n = wid - rel * NN;
  const int* cs = csAll + (size_t)rel * NE;
  const float* als = als3 + (size_t)rel * NN * 4;
  const float* ald = ald3 + (size_t)rel * NN * 4;
  float* ew = ew3 + (size_t)rel * NE * 4;
  int rs = rpA[rel * (NN + 1) + n];
  int re = rpA[rel * (NN + 1) + n + 1];
  int head = lane & 3;
  int el = lane >> 2;
  float ad = ald[n * 4 + head];
  float ws = 0.f;
  for (int base = rs; base < re; base += 16) {
    int e = base + el;
    float w = 0.f;
    if (e < re) {
      int s = cs[e];
      w = edge_w(als[s * 4 + head] + ad);
      ew[(size_t)e * 4 + head] = w;
    }
    ws += w;
  }
  ws += __shfl_xor(ws, 4);
  ws += __shfl_xor(ws, 8);
  ws += __shfl_xor(ws, 16);
  ws += __shfl_xor(ws, 32);
  float wself = 0.f;
  if (rel > 0) wself = edge_w(als[n * 4 + head] + ad);
  if (lane < 4) {
    ewself3[((size_t)rel * NN + n) * 4 + head] = wself;
    wsum3[((size_t)rel * NN + n) * 4 + head] = ws + wself;
  }
}

// ---------------- fused 3-relation gather (precomputed weights) ----------------
template<bool SL>
__device__ __forceinline__ void gat_rel(int n, int head, size_t loff,
                                        const __half* __restrict__ h,
                                        const float* __restrict__ ew,
                                        const float* __restrict__ wsum,
                                        const float* __restrict__ ewself,
                                        const int* __restrict__ rp,
                                        const int* __restrict__ cs,
                                        float& ox, float& oy, float& oz, float& ow) {
  int rs = rp[n], re = rp[n + 1];
  float ax = 0.f, ay = 0.f, az = 0.f, aw = 0.f;
  int i = rs;
  for (; i + 8 <= re; i += 8) {
    int s[8];
#pragma unroll
    for (int j = 0; j < 8; ++j) s[j] = cs[i + j];
    float w[8];
#pragma unroll
    for (int j = 0; j < 8; ++j) w[j] = ew[(size_t)(i + j) * 4 + head];
    h4 v[8];
#pragma unroll
    for (int j = 0; j < 8; ++j) v[j] = *(const h4*)&h[(size_t)s[j] * HCC + loff];
#pragma unroll
    for (int j = 0; j < 8; ++j) {
      ax = fmaf(w[j], __half2float(v[j].x), ax);
      ay = fmaf(w[j], __half2float(v[j].y), ay);
      az = fmaf(w[j], __half2float(v[j].z), az);
      aw = fmaf(w[j], __half2float(v[j].w), aw);
    }
  }
  for (; i < re; ++i) {
    int s = cs[i];
    float w = ew[(size_t)i * 4 + head];
    h4 hv = *(const h4*)&h[(size_t)s * HCC + loff];
    ax = fmaf(w, __half2float(hv.x), ax);
    ay = fmaf(w, __half2float(hv.y), ay);
    az = fmaf(w, __half2float(hv.z), az);
    aw = fmaf(w, __half2float(hv.w), aw);
  }
  if (SL) {
    float w = ewself[n * 4 + head];
    h4 hv = *(const h4*)&h[(size_t)n * HCC + loff];
    ax = fmaf(w, __half2float(hv.x), ax);
    ay = fmaf(w, __half2float(hv.y), ay);
    az = fmaf(w, __half2float(hv.z), az);
    aw = fmaf(w, __half2float(hv.w), aw);
  }
  float inv = 1.0f / (wsum[n * 4 + head] + 1e-16f);
  ox = fmaf(ax, inv, ox);
  oy = fmaf(ay, inv, oy);
  oz = fmaf(az, inv, oz);
  ow = fmaf(aw, inv, ow);
}

// CONCAT: o1hi/o1lo[n,256] = split-bf16 relu(sum_r gat + sum_r bias)
// !CONCAT: o32[n,64] = fp32 head-mean + sum_r bias
template<bool CONCAT>
__global__ __launch_bounds__(256) void k_gather3(const __half* __restrict__ h3,
                                                 const float* __restrict__ ew3,
                                                 const float* __restrict__ wsum3,
                                                 const float* __restrict__ ewself3,
                                                 const int* __restrict__ rpA,
                                                 const int* __restrict__ csAll,
                                                 const float* __restrict__ bias,
                                                 short* __restrict__ o1hi,
                                                 short* __restrict__ o1lo,
                                                 float* __restrict__ o32) {
  int gid = blockIdx.x * blockDim.x + threadIdx.x;
  int n = gid >> 6;
  int lane = threadIdx.x & 63;
  if (n >= NN) return;
  int head = lane >> 4;
  size_t loff = (size_t)lane * 4;
  const size_t HS = (size_t)NN * HCC;
  const size_t AS = (size_t)NN * 4;
  const size_t ES = (size_t)NE * 4;
  float ox = 0.f, oy = 0.f, oz = 0.f, ow = 0.f;
  gat_rel<false>(n, head, loff, h3,          ew3,          wsum3,          ewself3,          rpA,                csAll,          ox, oy, oz, ow);
  gat_rel<true >(n, head, loff, h3 + HS,     ew3 + ES,     wsum3 + AS,     ewself3 + AS,     rpA + (NN + 1),     csAll + NE,     ox, oy, oz, ow);
  gat_rel<true >(n, head, loff, h3 + 2 * HS, ew3 + 2 * ES, wsum3 + 2 * AS, ewself3 + 2 * AS, rpA + 2 * (NN + 1), csAll + 2 * NE, ox, oy, oz, ow);
  if (CONCAT) {
    float4 b0 = *(const float4*)&bias[lane * 4];
    float4 b1 = *(const float4*)&bias[HCC + lane * 4];
    float4 b2 = *(const float4*)&bias[2 * HCC + lane * 4];
    float vv[4];
    vv[0] = fmaxf(ox + b0.x + b1.x + b2.x, 0.f);
    vv[1] = fmaxf(oy + b0.y + b1.y + b2.y, 0.f);
    vv[2] = fmaxf(oz + b0.z + b1.z + b2.z, 0.f);
    vv[3] = fmaxf(ow + b0.w + b1.w + b2.w, 0.f);
    s4 hv, lv;
    short* hp = (short*)&hv;
    short* lp = (short*)&lv;
#pragma unroll
    for (int j = 0; j < 4; ++j) {
      unsigned short hb = bf_rne(vv[j]);
      float hf = __uint_as_float(((unsigned)hb) << 16);
      hp[j] = (short)hb;
      lp[j] = (short)bf_rne(vv[j] - hf);
    }
    *(s4*)&o1hi[(size_t)n * HCC + loff] = hv;
    *(s4*)&o1lo[(size_t)n * HCC + loff] = lv;
  } else {
    ox += __shfl_xor(ox, 16); oy += __shfl_xor(oy, 16);
    oz += __shfl_xor(oz, 16); ow += __shfl_xor(ow, 16);
    ox += __shfl_xor(ox, 32); oy += __shfl_xor(oy, 32);
    oz += __shfl_xor(oz, 32); ow += __shfl_xor(ow, 32);
    if (lane < 16) {
      float4 b0 = *(const float4*)&bias[lane * 4];
      float4 b1 = *(const float4*)&bias[OC + lane * 4];
      float4 b2 = *(const float4*)&bias[2 * OC + lane * 4];
      float4 o;
      o.x = 0.25f * ox + b0.x + b1.x + b2.x;
      o.y = 0.25f * oy + b0.y + b1.y + b2.y;
      o.z = 0.25f * oz + b0.z + b1.z + b2.z;
      o.w = 0.25f * ow + b0.w + b1.w + b2.w;
      *(float4*)&o32[(size_t)n * OC + lane * 4] = o;
    }
  }
}

// ---------------- final: out = relu(out2) @ Wl + bl ----------------
__global__ __launch_bounds__(256) void k_final(const float* __restrict__ out2,
                                               const float* __restrict__ Wl,
                                               const float* __restrict__ bl,
                                               float* __restrict__ outp) {
  __shared__ float Ws[64 * 64];
  __shared__ float bs[64];
  int tid = threadIdx.x;
  for (int i = tid; i < 4096; i += 256) Ws[i] = Wl[i];
  if (tid < 64) bs[tid] = bl[tid];
  __syncthreads();
  int r = blockIdx.x * 4 + (tid >> 6);
  int c = tid & 63;
  if (r >= NN) return;
  const float* xr = &out2[(size_t)r * OC];
  float acc = bs[c];
#pragma unroll
  for (int k = 0; k < 64; ++k) {
    float xv = xr[k];
    xv = (xv > 0.f) ? xv : 0.f;
    acc = fmaf(xv, Ws[k * 64 + c], acc);
  }
  outp[(size_t)r * OC + c] = acc;
}

extern "C" void kernel_launch(void* const* d_in, const int* in_sizes, int n_in,
                              void* d_out, int out_size, void* d_ws, size_t ws_size,
                              hipStream_t stream) {
  const float* x   = (const float*)d_in[0];
  const int* e_b   = (const int*)d_in[1];
  const int* e_sp  = (const int*)d_in[2];
  const int* e_si  = (const int*)d_in[3];
  const float* W1  = (const float*)d_in[4];
  const float* a1s = (const float*)d_in[5];
  const float* a1d = (const float*)d_in[6];
  const float* b1  = (const float*)d_in[7];
  const float* W2  = (const float*)d_in[8];
  const float* a2s = (const float*)d_in[9];
  const float* a2d = (const float*)d_in[10];
  const float* b2  = (const float*)d_in[11];
  const float* Wl  = (const float*)d_in[12];
  const float* bl  = (const float*)d_in[13];
  float* out = (float*)d_out;

  char* ws = (char*)d_ws;
  size_t off = 0;
  auto alloc = [&](size_t b) {
    char* p = ws + off;
    off += (b + 255) & ~(size_t)255;
    return p;
  };
  __half* h3  = (__half*)alloc((size_t)3 * NN * HCC * 2);   // 76.8 MB
  short* o1hi = (short*)alloc((size_t)NN * HCC * 2);        // 25.6 MB
  short* o1lo = (short*)alloc((size_t)NN * HCC * 2);        // 25.6 MB
  float* out2 = (float*)o1hi;  // alias: o1hi dead when out2 is written
  // union region: xhi/xlo (layer-1 A) then ew3 (per-layer edge weights)
  char* U = alloc((size_t)3 * NE * 4 * 4);                  // 38.4 MB
  short* xhi = (short*)U;
  short* xlo = (short*)(U + (size_t)NN * FIN * 2);
  float* ew3 = (float*)U;
  float* als3 = (float*)alloc((size_t)3 * NN * 4 * 4);
  float* ald3 = (float*)alloc((size_t)3 * NN * 4 * 4);
  float* wsum3 = (float*)alloc((size_t)3 * NN * 4 * 4);
  float* ewself3 = (float*)alloc((size_t)3 * NN * 4 * 4);
  int* deg3    = (int*)alloc((size_t)NT3 * 4);
  int* cursor3 = (int*)alloc((size_t)NT3 * 4);
  int* rpA     = (int*)alloc((size_t)3 * (NN + 1) * 4);
  int* bsum    = (int*)alloc(256 * 4);
  int* boffs   = (int*)alloc(256 * 4);
  short* Wc1   = (short*)alloc((size_t)3 * 4 * FIN * 128 * 2);
  short* Wc2   = (short*)alloc((size_t)3 * 4 * HCC * 128 * 2);
  int* csAll   = (int*)alloc((size_t)3 * NE * 4);

  // weight pre-split + x pre-split (tiny)
  k_prep<FIN><<<(3 * FIN * 256 + 255) / 256, 256, 0, stream>>>(W1, Wc1);
  k_prep<HCC><<<(3 * HCC * 256 + 255) / 256, 256, 0, stream>>>(W2, Wc2);
  k_split<<<(NN * FIN / 4 + 255) / 256, 256, 0, stream>>>(x, xhi, xlo);

  // CSR build
  hipMemsetAsync(deg3, 0, (size_t)NT3 * 4, stream);
  k_hist3<<<2048, 256, 0, stream>>>(e_b, e_sp, e_si, deg3);
  const int NB = (NT3 + 1023) / 1024;  // 147
  k_bsum<<<NB, 1024, 0, stream>>>(deg3, bsum);
  k_scan2<<<1, 256, 0, stream>>>(bsum, boffs, NB);
  k_rowptr<<<NB, 1024, 0, stream>>>(deg3, boffs, rpA, cursor3);
  k_scatter3<<<2048, 256, 0, stream>>>(e_b, e_sp, e_si, cursor3, csAll);

  const int gblocks = (NN + 63) / 64;   // 782
  const int ablocks = (NN * 64) / 256;  // 12500
  const int eblocks = (NT3 + 3) / 4;    // waves = 3*NN

  // layer 1
  k_mgemm<FIN><<<dim3(gblocks, 3), 256, 0, stream>>>(
      xhi, xlo, Wc1, a1s, a1d, h3, als3, ald3, NN);
  k_ew3<<<eblocks, 256, 0, stream>>>(als3, ald3, rpA, csAll, ew3, wsum3, ewself3);
  k_gather3<true><<<ablocks, 256, 0, stream>>>(
      h3, ew3, wsum3, ewself3, rpA, csAll, b1, o1hi, o1lo, nullptr);

  // layer 2
  k_mgemm<HCC><<<dim3(gblocks, 3), 256, 0, stream>>>(
      o1hi, o1lo, Wc2, a2s, a2d, h3, als3, ald3, NN);
  k_ew3<<<eblocks, 256, 0, stream>>>(als3, ald3, rpA, csAll, ew3, wsum3, ewself3);
  k_gather3<false><<<ablocks, 256, 0, stream>>>(
      h3, ew3, wsum3, ewself3, rpA, csAll, b2, nullptr, nullptr, out2);

  // final linear (relu on out2 fused)
  k_final<<<(NN + 3) / 4, 256, 0, stream>>>(out2, Wl, bl, out);
}

// Round 8
// 940.229 us; speedup vs baseline: 1.0724x; 1.0724x over previous
//
#include <hip/hip_runtime.h>
#include <hip/hip_bf16.h>
#include <hip/hip_fp16.h>

#define NN 50000
#define NE 800000
#define FIN 128
#define HCC 256   // HEADS*HID
#define OC 64
#define NSL 0.2f
#define NT3 (3 * NN)

typedef __attribute__((ext_vector_type(8))) short sh8;
typedef __attribute__((ext_vector_type(16))) float f32x16;

struct __attribute__((aligned(8))) h4 { __half x, y, z, w; };
struct __attribute__((aligned(8))) s4 { short x, y, z, w; };

__device__ __forceinline__ unsigned short bf_rne(float f) {
  unsigned u = __float_as_uint(f);
  u += 0x7FFF + ((u >> 16) & 1);
  return (unsigned short)(u >> 16);
}

__device__ __forceinline__ float edge_w(float lg) {
  lg = (lg > 0.f) ? lg : NSL * lg;
  return __expf(lg);
}

// -------- weight pre-split into chunked-coalesced layout --------
// W:[3][KK][256] fp32 -> out:[3][cb(2)][hl(2)][KK/8][c(128)][8] bf16
template<int KK>
__global__ __launch_bounds__(256) void k_prep(const float* __restrict__ W,
                                              short* __restrict__ out) {
  int i = blockIdx.x * 256 + threadIdx.x;
  if (i >= 3 * KK * 256) return;
  int r = i / (KK * 256);
  int rem = i - r * KK * 256;
  int k = rem >> 8;
  int n = rem & 255;
  float f = W[i];
  unsigned short hb = bf_rne(f);
  float hf = __uint_as_float(((unsigned)hb) << 16);
  unsigned short lb = bf_rne(f - hf);
  int cb = n >> 7, c = n & 127, ks8 = k >> 3, kj = k & 7;
  size_t base = (size_t)r * 4 * KK * 128;
  size_t oh = base + ((size_t)((cb * 2 + 0) * (KK / 8) + ks8) * 128 + c) * 8 + kj;
  size_t ol = base + ((size_t)((cb * 2 + 1) * (KK / 8) + ks8) * 128 + c) * 8 + kj;
  out[oh] = (short)hb;
  out[ol] = (short)lb;
}

// -------- x fp32 -> bf16 hi/lo --------
__global__ __launch_bounds__(256) void k_split(const float* __restrict__ x,
                                               short* __restrict__ xhi,
                                               short* __restrict__ xlo) {
  int i = blockIdx.x * 256 + threadIdx.x;
  if (i >= NN * FIN / 4) return;
  float4 v = ((const float4*)x)[i];
  s4 h, l;
  float f, hf;
  f = v.x; h.x = (short)bf_rne(f); hf = __uint_as_float(((unsigned)(unsigned short)h.x) << 16); l.x = (short)bf_rne(f - hf);
  f = v.y; h.y = (short)bf_rne(f); hf = __uint_as_float(((unsigned)(unsigned short)h.y) << 16); l.y = (short)bf_rne(f - hf);
  f = v.z; h.z = (short)bf_rne(f); hf = __uint_as_float(((unsigned)(unsigned short)h.z) << 16); l.z = (short)bf_rne(f - hf);
  f = v.w; h.w = (short)bf_rne(f); hf = __uint_as_float(((unsigned)(unsigned short)h.w) << 16); l.w = (short)bf_rne(f - hf);
  ((s4*)xhi)[i] = h;
  ((s4*)xlo)[i] = l;
}

// ---------------- CSR build ----------------
__global__ void k_hist3(const int* __restrict__ e0, const int* __restrict__ e1,
                        const int* __restrict__ e2, int* __restrict__ deg3) {
  int i = blockIdx.x * blockDim.x + threadIdx.x;
  int st = gridDim.x * blockDim.x;
  for (; i < 3 * NE; i += st) {
    int rel = i / NE;
    int j = i - rel * NE;
    const int* e = (rel == 0) ? e0 : ((rel == 1) ? e1 : e2);
    atomicAdd(&deg3[rel * NN + e[NE + j]], 1);
  }
}

__global__ __launch_bounds__(1024) void k_bsum(const int* __restrict__ deg3,
                                               int* __restrict__ bsum) {
  __shared__ int s[1024];
  int t = threadIdx.x;
  int i = blockIdx.x * 1024 + t;
  s[t] = (i < NT3) ? deg3[i] : 0;
  __syncthreads();
  for (int off = 512; off > 0; off >>= 1) {
    if (t < off) s[t] += s[t + off];
    __syncthreads();
  }
  if (t == 0) bsum[blockIdx.x] = s[0];
}

__global__ __launch_bounds__(256) void k_scan2(const int* __restrict__ bsum,
                                               int* __restrict__ boffs, int nb) {
  __shared__ int s[256];
  int t = threadIdx.x;
  int v = (t < nb) ? bsum[t] : 0;
  s[t] = v;
  __syncthreads();
  for (int off = 1; off < 256; off <<= 1) {
    int x = (t >= off) ? s[t - off] : 0;
    __syncthreads();
    s[t] += x;
    __syncthreads();
  }
  if (t < nb) boffs[t] = s[t] - v;  // exclusive
}

__global__ __launch_bounds__(1024) void k_rowptr(const int* __restrict__ deg3,
                                                 const int* __restrict__ boffs,
                                                 int* __restrict__ rpA,
                                                 int* __restrict__ cursor3) {
  __shared__ int s[1024];
  int t = threadIdx.x;
  int i = blockIdx.x * 1024 + t;
  int d = (i < NT3) ? deg3[i] : 0;
  s[t] = d;
  __syncthreads();
  for (int off = 1; off < 1024; off <<= 1) {
    int x = (t >= off) ? s[t - off] : 0;
    __syncthreads();
    s[t] += x;
    __syncthreads();
  }
  if (i < NT3) {
    int excl = boffs[blockIdx.x] + s[t] - d;
    int r = (i < NN) ? 0 : ((i < 2 * NN) ? 1 : 2);
    int n = i - r * NN;
    int val = excl - r * NE;
    rpA[r * (NN + 1) + n] = val;
    cursor3[i] = val;
  }
  if (blockIdx.x == 0 && t < 3) rpA[t * (NN + 1) + NN] = NE;
}

// one relation per launch: random-write region (3.2 MB) stays L2-resident
__global__ void k_scatter(const int* __restrict__ srcv, const int* __restrict__ dstv,
                          int* __restrict__ cursor, int* __restrict__ csr_src, int n) {
  int i = blockIdx.x * blockDim.x + threadIdx.x;
  int st = gridDim.x * blockDim.x;
  for (; i < n; i += st) {
    int pos = atomicAdd(&cursor[dstv[i]], 1);
    csr_src[pos] = srcv[i];
  }
}

// -------- split-bf16 MFMA GEMM (32x32x16), pre-split A, 3 relations, alpha fused ----
template<int KK>
__global__ __launch_bounds__(256) void k_mgemm(const short* __restrict__ Ahi,
                                               const short* __restrict__ Alo,
                                               const short* __restrict__ BcAll,
                                               const float* __restrict__ asfAll,
                                               const float* __restrict__ adfAll,
                                               __half* __restrict__ houtAll,
                                               float* __restrict__ alsAll,
                                               float* __restrict__ aldAll, int M) {
  const int rel = blockIdx.y;
  const short* Bc = BcAll + (size_t)rel * 4 * KK * 128;
  const float* asf = asfAll + rel * HCC;
  const float* adf = adfAll + rel * HCC;
  __half* hout = houtAll + (size_t)rel * NN * HCC;
  float* als = alsAll + (size_t)rel * NN * 4;
  float* ald = aldAll + (size_t)rel * NN * 4;

  const int tid = threadIdx.x;
  const int lane = tid & 63;
  const int w = tid >> 6;
  const int l31 = lane & 31;
  const int lg = lane >> 5;
  const int wrow = blockIdx.x * 64 + (w & 1) * 32;
  const int ch = w >> 1;

  f32x16 acc[4];
#pragma unroll
  for (int t = 0; t < 4; ++t) acc[t] = (f32x16)(0.f);

  const int r = wrow + l31;
  const bool aok = r < M;
  const short* ahp = Ahi + (size_t)r * KK;
  const short* alp = Alo + (size_t)r * KK;
  const short* bh = Bc + (size_t)(ch * 2 + 0) * KK * 128 + l31 * 8;
  const short* bl = Bc + (size_t)(ch * 2 + 1) * KK * 128 + l31 * 8;

#pragma unroll 2
  for (int kst = 0; kst < KK / 16; ++kst) {
    const int k0 = kst * 16 + lg * 8;
    sh8 ahi = {0, 0, 0, 0, 0, 0, 0, 0}, alo = ahi;
    if (aok) {
      ahi = *(const sh8*)(ahp + k0);
      alo = *(const sh8*)(alp + k0);
    }
    const int ks8 = kst * 2 + lg;
    const short* bhp = bh + (size_t)ks8 * 1024;
    const short* blp = bl + (size_t)ks8 * 1024;
    sh8 bhf[4], blf[4];
#pragma unroll
    for (int t = 0; t < 4; ++t) {
      bhf[t] = *(const sh8*)(bhp + t * 256);
      blf[t] = *(const sh8*)(blp + t * 256);
    }
#pragma unroll
    for (int t = 0; t < 4; ++t) {
      acc[t] = __builtin_amdgcn_mfma_f32_32x32x16_bf16(ahi, bhf[t], acc[t], 0, 0, 0);
      acc[t] = __builtin_amdgcn_mfma_f32_32x32x16_bf16(alo, bhf[t], acc[t], 0, 0, 0);
      acc[t] = __builtin_amdgcn_mfma_f32_32x32x16_bf16(ahi, blf[t], acc[t], 0, 0, 0);
    }
  }

  // epilogue: h (fp16) store + fused alpha (2 heads per col-half)
  float asr[4], adr[4];
#pragma unroll
  for (int t = 0; t < 4; ++t) {
    int col = ch * 128 + t * 32 + l31;
    asr[t] = asf[col];
    adr[t] = adf[col];
  }
#pragma unroll
  for (int v = 0; v < 16; ++v) {
    const int rl = (v & 3) + 8 * (v >> 2) + 4 * lg;
    const int row = wrow + rl;
    const bool rok = row < M;
    float s0 = 0.f, s1 = 0.f, d0 = 0.f, d1 = 0.f;
    __half* hp = hout + (size_t)row * 256 + ch * 128 + l31;
#pragma unroll
    for (int t = 0; t < 4; ++t) {
      float dv = acc[t][v];
      if (rok) hp[t * 32] = __float2half(dv);
      if (t < 2) { s0 += dv * asr[t]; d0 += dv * adr[t]; }
      else       { s1 += dv * asr[t]; d1 += dv * adr[t]; }
    }
#pragma unroll
    for (int m = 1; m < 32; m <<= 1) {
      s0 += __shfl_xor(s0, m);
      s1 += __shfl_xor(s1, m);
      d0 += __shfl_xor(d0, m);
      d1 += __shfl_xor(d1, m);
    }
    if (rok && l31 == 0) {
      *(float2*)(als + (size_t)row * 4 + ch * 2) = make_float2(s0, s1);
      *(float2*)(ald + (size_t)row * 4 + ch * 2) = make_float2(d0, d1);
    }
  }
}

// ---------------- fused 3-relation gather (inline weights, 8-deep) ----------------
template<bool SL>
__device__ __forceinline__ void gat_rel(int n, int head, size_t loff,
                                        const __half* __restrict__ h,
                                        const float* __restrict__ als,
                                        const float* __restrict__ ald,
                                        const int* __restrict__ rp,
                                        const int* __restrict__ cs,
                                        float& ox, float& oy, float& oz, float& ow) {
  float ad = ald[n * 4 + head];
  int rs = rp[n], re = rp[n + 1];
  float ax = 0.f, ay = 0.f, az = 0.f, aw = 0.f, wsum = 0.f;
  int i = rs;
  for (; i + 8 <= re; i += 8) {
    int s[8];
#pragma unroll
    for (int j = 0; j < 8; ++j) s[j] = cs[i + j];
    float al[8];
#pragma unroll
    for (int j = 0; j < 8; ++j) al[j] = als[s[j] * 4 + head];
    h4 v[8];
#pragma unroll
    for (int j = 0; j < 8; ++j) v[j] = *(const h4*)&h[(size_t)s[j] * HCC + loff];
#pragma unroll
    for (int j = 0; j < 8; ++j) {
      float w = edge_w(al[j] + ad);
      wsum += w;
      ax = fmaf(w, __half2float(v[j].x), ax);
      ay = fmaf(w, __half2float(v[j].y), ay);
      az = fmaf(w, __half2float(v[j].z), az);
      aw = fmaf(w, __half2float(v[j].w), aw);
    }
  }
  for (; i < re; ++i) {
    int s = cs[i];
    float w = edge_w(als[s * 4 + head] + ad);
    wsum += w;
    h4 hv = *(const h4*)&h[(size_t)s * HCC + loff];
    ax = fmaf(w, __half2float(hv.x), ax);
    ay = fmaf(w, __half2float(hv.y), ay);
    az = fmaf(w, __half2float(hv.z), az);
    aw = fmaf(w, __half2float(hv.w), aw);
  }
  if (SL) {
    float w = edge_w(als[n * 4 + head] + ad);
    wsum += w;
    h4 hv = *(const h4*)&h[(size_t)n * HCC + loff];
    ax = fmaf(w, __half2float(hv.x), ax);
    ay = fmaf(w, __half2float(hv.y), ay);
    az = fmaf(w, __half2float(hv.z), az);
    aw = fmaf(w, __half2float(hv.w), aw);
  }
  float inv = 1.0f / (wsum + 1e-16f);
  ox = fmaf(ax, inv, ox);
  oy = fmaf(ay, inv, oy);
  oz = fmaf(az, inv, oz);
  ow = fmaf(aw, inv, ow);
}

// CONCAT: o1hi/o1lo[n,256] = split-bf16 relu(sum_r gat + sum_r bias)
// !CONCAT: o32[n,64] = fp32 head-mean + sum_r bias
template<bool CONCAT>
__global__ __launch_bounds__(256) void k_gather3(const __half* __restrict__ h3,
                                                 const float* __restrict__ als3,
                                                 const float* __restrict__ ald3,
                                                 const int* __restrict__ rpA,
                                                 const int* __restrict__ csAll,
                                                 const float* __restrict__ bias,
                                                 short* __restrict__ o1hi,
                                                 short* __restrict__ o1lo,
                                                 float* __restrict__ o32) {
  int gid = blockIdx.x * blockDim.x + threadIdx.x;
  int n = gid >> 6;
  int lane = threadIdx.x & 63;
  if (n >= NN) return;
  int head = lane >> 4;
  size_t loff = (size_t)lane * 4;
  const size_t HS = (size_t)NN * HCC;
  const size_t AS = (size_t)NN * 4;
  float ox = 0.f, oy = 0.f, oz = 0.f, ow = 0.f;
  gat_rel<false>(n, head, loff, h3,          als3,          ald3,          rpA,                csAll,          ox, oy, oz, ow);
  gat_rel<true >(n, head, loff, h3 + HS,     als3 + AS,     ald3 + AS,     rpA + (NN + 1),     csAll + NE,     ox, oy, oz, ow);
  gat_rel<true >(n, head, loff, h3 + 2 * HS, als3 + 2 * AS, ald3 + 2 * AS, rpA + 2 * (NN + 1), csAll + 2 * NE, ox, oy, oz, ow);
  if (CONCAT) {
    float4 b0 = *(const float4*)&bias[lane * 4];
    float4 b1 = *(const float4*)&bias[HCC + lane * 4];
    float4 b2 = *(const float4*)&bias[2 * HCC + lane * 4];
    float vv[4];
    vv[0] = fmaxf(ox + b0.x + b1.x + b2.x, 0.f);
    vv[1] = fmaxf(oy + b0.y + b1.y + b2.y, 0.f);
    vv[2] = fmaxf(oz + b0.z + b1.z + b2.z, 0.f);
    vv[3] = fmaxf(ow + b0.w + b1.w + b2.w, 0.f);
    s4 hv, lv;
    short* hp = (short*)&hv;
    short* lp = (short*)&lv;
#pragma unroll
    for (int j = 0; j < 4; ++j) {
      unsigned short hb = bf_rne(vv[j]);
      float hf = __uint_as_float(((unsigned)hb) << 16);
      hp[j] = (short)hb;
      lp[j] = (short)bf_rne(vv[j] - hf);
    }
    *(s4*)&o1hi[(size_t)n * HCC + loff] = hv;
    *(s4*)&o1lo[(size_t)n * HCC + loff] = lv;
  } else {
    ox += __shfl_xor(ox, 16); oy += __shfl_xor(oy, 16);
    oz += __shfl_xor(oz, 16); ow += __shfl_xor(ow, 16);
    ox += __shfl_xor(ox, 32); oy += __shfl_xor(oy, 32);
    oz += __shfl_xor(oz, 32); ow += __shfl_xor(ow, 32);
    if (lane < 16) {
      float4 b0 = *(const float4*)&bias[lane * 4];
      float4 b1 = *(const float4*)&bias[OC + lane * 4];
      float4 b2 = *(const float4*)&bias[2 * OC + lane * 4];
      float4 o;
      o.x = 0.25f * ox + b0.x + b1.x + b2.x;
      o.y = 0.25f * oy + b0.y + b1.y + b2.y;
      o.z = 0.25f * oz + b0.z + b1.z + b2.z;
      o.w = 0.25f * ow + b0.w + b1.w + b2.w;
      *(float4*)&o32[(size_t)n * OC + lane * 4] = o;
    }
  }
}

// ---------------- final: out = relu(out2) @ Wl + bl ----------------
__global__ __launch_bounds__(256) void k_final(const float* __restrict__ out2,
                                               const float* __restrict__ Wl,
                                               const float* __restrict__ bl,
                                               float* __restrict__ outp) {
  __shared__ float Ws[64 * 64];
  __shared__ float bs[64];
  int tid = threadIdx.x;
  for (int i = tid; i < 4096; i += 256) Ws[i] = Wl[i];
  if (tid < 64) bs[tid] = bl[tid];
  __syncthreads();
  int r = blockIdx.x * 4 + (tid >> 6);
  int c = tid & 63;
  if (r >= NN) return;
  const float* xr = &out2[(size_t)r * OC];
  float acc = bs[c];
#pragma unroll
  for (int k = 0; k < 64; ++k) {
    float xv = xr[k];
    xv = (xv > 0.f) ? xv : 0.f;
    acc = fmaf(xv, Ws[k * 64 + c], acc);
  }
  outp[(size_t)r * OC + c] = acc;
}

extern "C" void kernel_launch(void* const* d_in, const int* in_sizes, int n_in,
                              void* d_out, int out_size, void* d_ws, size_t ws_size,
                              hipStream_t stream) {
  const float* x   = (const float*)d_in[0];
  const int* e_b   = (const int*)d_in[1];
  const int* e_sp  = (const int*)d_in[2];
  const int* e_si  = (const int*)d_in[3];
  const float* W1  = (const float*)d_in[4];
  const float* a1s = (const float*)d_in[5];
  const float* a1d = (const float*)d_in[6];
  const float* b1  = (const float*)d_in[7];
  const float* W2  = (const float*)d_in[8];
  const float* a2s = (const float*)d_in[9];
  const float* a2d = (const float*)d_in[10];
  const float* b2  = (const float*)d_in[11];
  const float* Wl  = (const float*)d_in[12];
  const float* bl  = (const float*)d_in[13];
  float* out = (float*)d_out;

  char* ws = (char*)d_ws;
  size_t off = 0;
  auto alloc = [&](size_t b) {
    char* p = ws + off;
    off += (b + 255) & ~(size_t)255;
    return p;
  };
  __half* h3  = (__half*)alloc((size_t)3 * NN * HCC * 2);   // 76.8 MB
  short* o1hi = (short*)alloc((size_t)NN * HCC * 2);        // 25.6 MB
  short* o1lo = (short*)alloc((size_t)NN * HCC * 2);        // 25.6 MB
  float* out2 = (float*)o1hi;  // alias: o1hi dead when out2 is written
  short* xhi  = (short*)alloc((size_t)NN * FIN * 2);        // 12.8 MB
  short* xlo  = (short*)alloc((size_t)NN * FIN * 2);        // 12.8 MB
  float* als3 = (float*)alloc((size_t)3 * NN * 4 * 4);
  float* ald3 = (float*)alloc((size_t)3 * NN * 4 * 4);
  int* deg3    = (int*)alloc((size_t)NT3 * 4);
  int* cursor3 = (int*)alloc((size_t)NT3 * 4);
  int* rpA     = (int*)alloc((size_t)3 * (NN + 1) * 4);
  int* bsum    = (int*)alloc(256 * 4);
  int* boffs   = (int*)alloc(256 * 4);
  short* Wc1   = (short*)alloc((size_t)3 * 4 * FIN * 128 * 2);
  short* Wc2   = (short*)alloc((size_t)3 * 4 * HCC * 128 * 2);
  int* csAll   = (int*)alloc((size_t)3 * NE * 4);

  const int* edges[3] = {e_b, e_sp, e_si};

  // weight pre-split + x pre-split (tiny)
  k_prep<FIN><<<(3 * FIN * 256 + 255) / 256, 256, 0, stream>>>(W1, Wc1);
  k_prep<HCC><<<(3 * HCC * 256 + 255) / 256, 256, 0, stream>>>(W2, Wc2);
  k_split<<<(NN * FIN / 4 + 255) / 256, 256, 0, stream>>>(x, xhi, xlo);

  // CSR build
  hipMemsetAsync(deg3, 0, (size_t)NT3 * 4, stream);
  k_hist3<<<2048, 256, 0, stream>>>(e_b, e_sp, e_si, deg3);
  const int NB = (NT3 + 1023) / 1024;  // 147
  k_bsum<<<NB, 1024, 0, stream>>>(deg3, bsum);
  k_scan2<<<1, 256, 0, stream>>>(bsum, boffs, NB);
  k_rowptr<<<NB, 1024, 0, stream>>>(deg3, boffs, rpA, cursor3);
  for (int r = 0; r < 3; ++r)
    k_scatter<<<1024, 256, 0, stream>>>(edges[r], edges[r] + NE, cursor3 + r * NN,
                                        csAll + (size_t)r * NE, NE);

  const int gblocks = (NN + 63) / 64;   // 782
  const int ablocks = (NN * 64) / 256;  // 12500

  // layer 1
  k_mgemm<FIN><<<dim3(gblocks, 3), 256, 0, stream>>>(
      xhi, xlo, Wc1, a1s, a1d, h3, als3, ald3, NN);
  k_gather3<true><<<ablocks, 256, 0, stream>>>(
      h3, als3, ald3, rpA, csAll, b1, o1hi, o1lo, nullptr);

  // layer 2
  k_mgemm<HCC><<<dim3(gblocks, 3), 256, 0, stream>>>(
      o1hi, o1lo, Wc2, a2s, a2d, h3, als3, ald3, NN);
  k_gather3<false><<<ablocks, 256, 0, stream>>>(
      h3, als3, ald3, rpA, csAll, b2, nullptr, nullptr, out2);

  // final linear (relu on out2 fused)
  k_final<<<(NN + 3) / 4, 256, 0, stream>>>(out2, Wl, bl, out);
}

// Round 9
// 887.946 us; speedup vs baseline: 1.1356x; 1.0589x over previous
//
#include <hip/hip_runtime.h>
#include <hip/hip_bf16.h>
#include <hip/hip_fp16.h>

#define NN 50000
#define NE 800000
#define FIN 128
#define HCC 256   // HEADS*HID
#define OC 64
#define NSL 0.2f
#define NT3 (3 * NN)

typedef __attribute__((ext_vector_type(8))) short sh8;
typedef __attribute__((ext_vector_type(16))) float f32x16;

struct __attribute__((aligned(8))) h4 { __half x, y, z, w; };
struct __attribute__((aligned(8))) s4 { short x, y, z, w; };

__device__ __forceinline__ unsigned short bf_rne(float f) {
  unsigned u = __float_as_uint(f);
  u += 0x7FFF + ((u >> 16) & 1);
  return (unsigned short)(u >> 16);
}

__device__ __forceinline__ float edge_w(float lg) {
  lg = (lg > 0.f) ? lg : NSL * lg;
  return __expf(lg);
}

// -------- weight pre-split into chunked-coalesced layout --------
// W:[3][KK][256] fp32 -> out:[3][cb(2)][hl(2)][KK/8][c(128)][8] bf16
template<int KK>
__global__ __launch_bounds__(256) void k_prep(const float* __restrict__ W,
                                              short* __restrict__ out) {
  int i = blockIdx.x * 256 + threadIdx.x;
  if (i >= 3 * KK * 256) return;
  int r = i / (KK * 256);
  int rem = i - r * KK * 256;
  int k = rem >> 8;
  int n = rem & 255;
  float f = W[i];
  unsigned short hb = bf_rne(f);
  float hf = __uint_as_float(((unsigned)hb) << 16);
  unsigned short lb = bf_rne(f - hf);
  int cb = n >> 7, c = n & 127, ks8 = k >> 3, kj = k & 7;
  size_t base = (size_t)r * 4 * KK * 128;
  size_t oh = base + ((size_t)((cb * 2 + 0) * (KK / 8) + ks8) * 128 + c) * 8 + kj;
  size_t ol = base + ((size_t)((cb * 2 + 1) * (KK / 8) + ks8) * 128 + c) * 8 + kj;
  out[oh] = (short)hb;
  out[ol] = (short)lb;
}

// -------- x fp32 -> bf16 hi/lo --------
__global__ __launch_bounds__(256) void k_split(const float* __restrict__ x,
                                               short* __restrict__ xhi,
                                               short* __restrict__ xlo) {
  int i = blockIdx.x * 256 + threadIdx.x;
  if (i >= NN * FIN / 4) return;
  float4 v = ((const float4*)x)[i];
  s4 h, l;
  float f, hf;
  f = v.x; h.x = (short)bf_rne(f); hf = __uint_as_float(((unsigned)(unsigned short)h.x) << 16); l.x = (short)bf_rne(f - hf);
  f = v.y; h.y = (short)bf_rne(f); hf = __uint_as_float(((unsigned)(unsigned short)h.y) << 16); l.y = (short)bf_rne(f - hf);
  f = v.z; h.z = (short)bf_rne(f); hf = __uint_as_float(((unsigned)(unsigned short)h.z) << 16); l.z = (short)bf_rne(f - hf);
  f = v.w; h.w = (short)bf_rne(f); hf = __uint_as_float(((unsigned)(unsigned short)h.w) << 16); l.w = (short)bf_rne(f - hf);
  ((s4*)xhi)[i] = h;
  ((s4*)xlo)[i] = l;
}

// ---------------- CSR build ----------------
__global__ void k_hist3(const int* __restrict__ e0, const int* __restrict__ e1,
                        const int* __restrict__ e2, int* __restrict__ deg3) {
  int i = blockIdx.x * blockDim.x + threadIdx.x;
  int st = gridDim.x * blockDim.x;
  for (; i < 3 * NE; i += st) {
    int rel = i / NE;
    int j = i - rel * NE;
    const int* e = (rel == 0) ? e0 : ((rel == 1) ? e1 : e2);
    atomicAdd(&deg3[rel * NN + e[NE + j]], 1);
  }
}

__global__ __launch_bounds__(1024) void k_bsum(const int* __restrict__ deg3,
                                               int* __restrict__ bsum) {
  __shared__ int s[1024];
  int t = threadIdx.x;
  int i = blockIdx.x * 1024 + t;
  s[t] = (i < NT3) ? deg3[i] : 0;
  __syncthreads();
  for (int off = 512; off > 0; off >>= 1) {
    if (t < off) s[t] += s[t + off];
    __syncthreads();
  }
  if (t == 0) bsum[blockIdx.x] = s[0];
}

__global__ __launch_bounds__(256) void k_scan2(const int* __restrict__ bsum,
                                               int* __restrict__ boffs, int nb) {
  __shared__ int s[256];
  int t = threadIdx.x;
  int v = (t < nb) ? bsum[t] : 0;
  s[t] = v;
  __syncthreads();
  for (int off = 1; off < 256; off <<= 1) {
    int x = (t >= off) ? s[t - off] : 0;
    __syncthreads();
    s[t] += x;
    __syncthreads();
  }
  if (t < nb) boffs[t] = s[t] - v;  // exclusive
}

__global__ __launch_bounds__(1024) void k_rowptr(const int* __restrict__ deg3,
                                                 const int* __restrict__ boffs,
                                                 int* __restrict__ rpA,
                                                 int* __restrict__ cursor3) {
  __shared__ int s[1024];
  int t = threadIdx.x;
  int i = blockIdx.x * 1024 + t;
  int d = (i < NT3) ? deg3[i] : 0;
  s[t] = d;
  __syncthreads();
  for (int off = 1; off < 1024; off <<= 1) {
    int x = (t >= off) ? s[t - off] : 0;
    __syncthreads();
    s[t] += x;
    __syncthreads();
  }
  if (i < NT3) {
    int excl = boffs[blockIdx.x] + s[t] - d;
    int r = (i < NN) ? 0 : ((i < 2 * NN) ? 1 : 2);
    int n = i - r * NN;
    int val = excl - r * NE;
    rpA[r * (NN + 1) + n] = val;
    cursor3[i] = val;
  }
  if (blockIdx.x == 0 && t < 3) rpA[t * (NN + 1) + NN] = NE;
}

// one relation per launch: random-write region (3.2 MB) stays L2-resident
__global__ void k_scatter(const int* __restrict__ srcv, const int* __restrict__ dstv,
                          int* __restrict__ cursor, int* __restrict__ csr_src, int n) {
  int i = blockIdx.x * blockDim.x + threadIdx.x;
  int st = gridDim.x * blockDim.x;
  for (; i < n; i += st) {
    int pos = atomicAdd(&cursor[dstv[i]], 1);
    csr_src[pos] = srcv[i];
  }
}

// -------- split-bf16 MFMA GEMM (32x32x16), pre-split A, 3 relations, alpha fused ----
template<int KK>
__global__ __launch_bounds__(256) void k_mgemm(const short* __restrict__ Ahi,
                                               const short* __restrict__ Alo,
                                               const short* __restrict__ BcAll,
                                               const float* __restrict__ asfAll,
                                               const float* __restrict__ adfAll,
                                               __half* __restrict__ houtAll,
                                               float* __restrict__ alsAll,
                                               float* __restrict__ aldAll, int M) {
  const int rel = blockIdx.y;
  const short* Bc = BcAll + (size_t)rel * 4 * KK * 128;
  const float* asf = asfAll + rel * HCC;
  const float* adf = adfAll + rel * HCC;
  __half* hout = houtAll + (size_t)rel * NN * HCC;
  float* als = alsAll + (size_t)rel * NN * 4;
  float* ald = aldAll + (size_t)rel * NN * 4;

  const int tid = threadIdx.x;
  const int lane = tid & 63;
  const int w = tid >> 6;
  const int l31 = lane & 31;
  const int lg = lane >> 5;
  const int wrow = blockIdx.x * 64 + (w & 1) * 32;
  const int ch = w >> 1;

  f32x16 acc[4];
#pragma unroll
  for (int t = 0; t < 4; ++t) acc[t] = (f32x16)(0.f);

  const int r = wrow + l31;
  const bool aok = r < M;
  const short* ahp = Ahi + (size_t)r * KK;
  const short* alp = Alo + (size_t)r * KK;
  const short* bh = Bc + (size_t)(ch * 2 + 0) * KK * 128 + l31 * 8;
  const short* bl = Bc + (size_t)(ch * 2 + 1) * KK * 128 + l31 * 8;

#pragma unroll 2
  for (int kst = 0; kst < KK / 16; ++kst) {
    const int k0 = kst * 16 + lg * 8;
    sh8 ahi = {0, 0, 0, 0, 0, 0, 0, 0}, alo = ahi;
    if (aok) {
      ahi = *(const sh8*)(ahp + k0);
      alo = *(const sh8*)(alp + k0);
    }
    const int ks8 = kst * 2 + lg;
    const short* bhp = bh + (size_t)ks8 * 1024;
    const short* blp = bl + (size_t)ks8 * 1024;
    sh8 bhf[4], blf[4];
#pragma unroll
    for (int t = 0; t < 4; ++t) {
      bhf[t] = *(const sh8*)(bhp + t * 256);
      blf[t] = *(const sh8*)(blp + t * 256);
    }
#pragma unroll
    for (int t = 0; t < 4; ++t) {
      acc[t] = __builtin_amdgcn_mfma_f32_32x32x16_bf16(ahi, bhf[t], acc[t], 0, 0, 0);
      acc[t] = __builtin_amdgcn_mfma_f32_32x32x16_bf16(alo, bhf[t], acc[t], 0, 0, 0);
      acc[t] = __builtin_amdgcn_mfma_f32_32x32x16_bf16(ahi, blf[t], acc[t], 0, 0, 0);
    }
  }

  // epilogue: h (fp16) store + fused alpha (2 heads per col-half)
  float asr[4], adr[4];
#pragma unroll
  for (int t = 0; t < 4; ++t) {
    int col = ch * 128 + t * 32 + l31;
    asr[t] = asf[col];
    adr[t] = adf[col];
  }
#pragma unroll
  for (int v = 0; v < 16; ++v) {
    const int rl = (v & 3) + 8 * (v >> 2) + 4 * lg;
    const int row = wrow + rl;
    const bool rok = row < M;
    float s0 = 0.f, s1 = 0.f, d0 = 0.f, d1 = 0.f;
    __half* hp = hout + (size_t)row * 256 + ch * 128 + l31;
#pragma unroll
    for (int t = 0; t < 4; ++t) {
      float dv = acc[t][v];
      if (rok) hp[t * 32] = __float2half(dv);
      if (t < 2) { s0 += dv * asr[t]; d0 += dv * adr[t]; }
      else       { s1 += dv * asr[t]; d1 += dv * adr[t]; }
    }
#pragma unroll
    for (int m = 1; m < 32; m <<= 1) {
      s0 += __shfl_xor(s0, m);
      s1 += __shfl_xor(s1, m);
      d0 += __shfl_xor(d0, m);
      d1 += __shfl_xor(d1, m);
    }
    if (rok && l31 == 0) {
      *(float2*)(als + (size_t)row * 4 + ch * 2) = make_float2(s0, s1);
      *(float2*)(ald + (size_t)row * 4 + ch * 2) = make_float2(d0, d1);
    }
  }
}

// ---------------- fused 3-relation gather (inline weights, 4-deep) ----------------
template<bool SL>
__device__ __forceinline__ void gat_rel(int n, int head, size_t loff,
                                        const __half* __restrict__ h,
                                        const float* __restrict__ als,
                                        const float* __restrict__ ald,
                                        const int* __restrict__ rp,
                                        const int* __restrict__ cs,
                                        float& ox, float& oy, float& oz, float& ow) {
  float ad = ald[n * 4 + head];
  int rs = rp[n], re = rp[n + 1];
  float ax = 0.f, ay = 0.f, az = 0.f, aw = 0.f, wsum = 0.f;
  int i = rs;
  for (; i + 4 <= re; i += 4) {
    int s0 = cs[i], s1 = cs[i + 1], s2 = cs[i + 2], s3 = cs[i + 3];
    float al0 = als[s0 * 4 + head];
    float al1 = als[s1 * 4 + head];
    float al2 = als[s2 * 4 + head];
    float al3 = als[s3 * 4 + head];
    h4 v0 = *(const h4*)&h[(size_t)s0 * HCC + loff];
    h4 v1 = *(const h4*)&h[(size_t)s1 * HCC + loff];
    h4 v2 = *(const h4*)&h[(size_t)s2 * HCC + loff];
    h4 v3 = *(const h4*)&h[(size_t)s3 * HCC + loff];
    float w0 = edge_w(al0 + ad), w1 = edge_w(al1 + ad);
    float w2 = edge_w(al2 + ad), w3 = edge_w(al3 + ad);
    wsum += (w0 + w1) + (w2 + w3);
    ax = fmaf(w0, __half2float(v0.x), ax); ay = fmaf(w0, __half2float(v0.y), ay);
    az = fmaf(w0, __half2float(v0.z), az); aw = fmaf(w0, __half2float(v0.w), aw);
    ax = fmaf(w1, __half2float(v1.x), ax); ay = fmaf(w1, __half2float(v1.y), ay);
    az = fmaf(w1, __half2float(v1.z), az); aw = fmaf(w1, __half2float(v1.w), aw);
    ax = fmaf(w2, __half2float(v2.x), ax); ay = fmaf(w2, __half2float(v2.y), ay);
    az = fmaf(w2, __half2float(v2.z), az); aw = fmaf(w2, __half2float(v2.w), aw);
    ax = fmaf(w3, __half2float(v3.x), ax); ay = fmaf(w3, __half2float(v3.y), ay);
    az = fmaf(w3, __half2float(v3.z), az); aw = fmaf(w3, __half2float(v3.w), aw);
  }
  for (; i < re; ++i) {
    int s = cs[i];
    float w = edge_w(als[s * 4 + head] + ad);
    wsum += w;
    h4 hv = *(const h4*)&h[(size_t)s * HCC + loff];
    ax = fmaf(w, __half2float(hv.x), ax);
    ay = fmaf(w, __half2float(hv.y), ay);
    az = fmaf(w, __half2float(hv.z), az);
    aw = fmaf(w, __half2float(hv.w), aw);
  }
  if (SL) {
    float w = edge_w(als[n * 4 + head] + ad);
    wsum += w;
    h4 hv = *(const h4*)&h[(size_t)n * HCC + loff];
    ax = fmaf(w, __half2float(hv.x), ax);
    ay = fmaf(w, __half2float(hv.y), ay);
    az = fmaf(w, __half2float(hv.z), az);
    aw = fmaf(w, __half2float(hv.w), aw);
  }
  float inv = 1.0f / (wsum + 1e-16f);
  ox = fmaf(ax, inv, ox);
  oy = fmaf(ay, inv, oy);
  oz = fmaf(az, inv, oz);
  ow = fmaf(aw, inv, ow);
}

// CONCAT: o1hi/o1lo[n,256] = split-bf16 relu(sum_r gat + sum_r bias)
// !CONCAT: fused final -> outp[n,64] = relu(mean + biases) @ Wl + bl
template<bool CONCAT>
__global__ __launch_bounds__(256) void k_gather3(const __half* __restrict__ h3,
                                                 const float* __restrict__ als3,
                                                 const float* __restrict__ ald3,
                                                 const int* __restrict__ rpA,
                                                 const int* __restrict__ csAll,
                                                 const float* __restrict__ bias,
                                                 short* __restrict__ o1hi,
                                                 short* __restrict__ o1lo,
                                                 const float* __restrict__ Wl,
                                                 const float* __restrict__ bl,
                                                 float* __restrict__ outp) {
  __shared__ float Ws[64 * 64];
  if (!CONCAT) {
    for (int i = threadIdx.x; i < 4096; i += 256) Ws[i] = Wl[i];
    __syncthreads();  // safe: grid covers exactly NN*64 threads, no early returns
  }
  int gid = blockIdx.x * blockDim.x + threadIdx.x;
  int n = gid >> 6;
  int lane = threadIdx.x & 63;
  if (n >= NN) return;
  int head = lane >> 4;
  size_t loff = (size_t)lane * 4;
  const size_t HS = (size_t)NN * HCC;
  const size_t AS = (size_t)NN * 4;
  float ox = 0.f, oy = 0.f, oz = 0.f, ow = 0.f;
  gat_rel<false>(n, head, loff, h3,          als3,          ald3,          rpA,                csAll,          ox, oy, oz, ow);
  gat_rel<true >(n, head, loff, h3 + HS,     als3 + AS,     ald3 + AS,     rpA + (NN + 1),     csAll + NE,     ox, oy, oz, ow);
  gat_rel<true >(n, head, loff, h3 + 2 * HS, als3 + 2 * AS, ald3 + 2 * AS, rpA + 2 * (NN + 1), csAll + 2 * NE, ox, oy, oz, ow);
  if (CONCAT) {
    float4 b0 = *(const float4*)&bias[lane * 4];
    float4 b1 = *(const float4*)&bias[HCC + lane * 4];
    float4 b2 = *(const float4*)&bias[2 * HCC + lane * 4];
    float vv[4];
    vv[0] = fmaxf(ox + b0.x + b1.x + b2.x, 0.f);
    vv[1] = fmaxf(oy + b0.y + b1.y + b2.y, 0.f);
    vv[2] = fmaxf(oz + b0.z + b1.z + b2.z, 0.f);
    vv[3] = fmaxf(ow + b0.w + b1.w + b2.w, 0.f);
    s4 hv, lv;
    short* hp = (short*)&hv;
    short* lp = (short*)&lv;
#pragma unroll
    for (int j = 0; j < 4; ++j) {
      unsigned short hb = bf_rne(vv[j]);
      float hf = __uint_as_float(((unsigned)hb) << 16);
      hp[j] = (short)hb;
      lp[j] = (short)bf_rne(vv[j] - hf);
    }
    *(s4*)&o1hi[(size_t)n * HCC + loff] = hv;
    *(s4*)&o1lo[(size_t)n * HCC + loff] = lv;
  } else {
    // butterfly: every lane ends with 4-head sums for within-head ch 4*(lane&15)+j
    ox += __shfl_xor(ox, 16); oy += __shfl_xor(oy, 16);
    oz += __shfl_xor(oz, 16); ow += __shfl_xor(ow, 16);
    ox += __shfl_xor(ox, 32); oy += __shfl_xor(oy, 32);
    oz += __shfl_xor(oz, 32); ow += __shfl_xor(ow, 32);
    int q0 = lane & 15;
    float4 b0 = *(const float4*)&bias[q0 * 4];
    float4 b1 = *(const float4*)&bias[OC + q0 * 4];
    float4 b2 = *(const float4*)&bias[2 * OC + q0 * 4];
    float x0 = fmaxf(0.25f * ox + b0.x + b1.x + b2.x, 0.f);
    float x1 = fmaxf(0.25f * oy + b0.y + b1.y + b2.y, 0.f);
    float x2 = fmaxf(0.25f * oz + b0.z + b1.z + b2.z, 0.f);
    float x3 = fmaxf(0.25f * ow + b0.w + b1.w + b2.w, 0.f);
    float acc = bl[lane];
#pragma unroll
    for (int q = 0; q < 16; ++q) {
      float xa = __shfl(x0, q);
      float xb = __shfl(x1, q);
      float xc = __shfl(x2, q);
      float xd = __shfl(x3, q);
      acc = fmaf(xa, Ws[(4 * q + 0) * 64 + lane], acc);
      acc = fmaf(xb, Ws[(4 * q + 1) * 64 + lane], acc);
      acc = fmaf(xc, Ws[(4 * q + 2) * 64 + lane], acc);
      acc = fmaf(xd, Ws[(4 * q + 3) * 64 + lane], acc);
    }
    outp[(size_t)n * OC + lane] = acc;
  }
}

extern "C" void kernel_launch(void* const* d_in, const int* in_sizes, int n_in,
                              void* d_out, int out_size, void* d_ws, size_t ws_size,
                              hipStream_t stream) {
  const float* x   = (const float*)d_in[0];
  const int* e_b   = (const int*)d_in[1];
  const int* e_sp  = (const int*)d_in[2];
  const int* e_si  = (const int*)d_in[3];
  const float* W1  = (const float*)d_in[4];
  const float* a1s = (const float*)d_in[5];
  const float* a1d = (const float*)d_in[6];
  const float* b1  = (const float*)d_in[7];
  const float* W2  = (const float*)d_in[8];
  const float* a2s = (const float*)d_in[9];
  const float* a2d = (const float*)d_in[10];
  const float* b2  = (const float*)d_in[11];
  const float* Wl  = (const float*)d_in[12];
  const float* bl  = (const float*)d_in[13];
  float* out = (float*)d_out;

  char* ws = (char*)d_ws;
  size_t off = 0;
  auto alloc = [&](size_t b) {
    char* p = ws + off;
    off += (b + 255) & ~(size_t)255;
    return p;
  };
  __half* h3  = (__half*)alloc((size_t)3 * NN * HCC * 2);   // 76.8 MB
  short* o1hi = (short*)alloc((size_t)NN * HCC * 2);        // 25.6 MB
  short* o1lo = (short*)alloc((size_t)NN * HCC * 2);        // 25.6 MB
  short* xhi  = (short*)alloc((size_t)NN * FIN * 2);        // 12.8 MB
  short* xlo  = (short*)alloc((size_t)NN * FIN * 2);        // 12.8 MB
  float* als3 = (float*)alloc((size_t)3 * NN * 4 * 4);
  float* ald3 = (float*)alloc((size_t)3 * NN * 4 * 4);
  int* deg3    = (int*)alloc((size_t)NT3 * 4);
  int* cursor3 = (int*)alloc((size_t)NT3 * 4);
  int* rpA     = (int*)alloc((size_t)3 * (NN + 1) * 4);
  int* bsum    = (int*)alloc(256 * 4);
  int* boffs   = (int*)alloc(256 * 4);
  short* Wc1   = (short*)alloc((size_t)3 * 4 * FIN * 128 * 2);
  short* Wc2   = (short*)alloc((size_t)3 * 4 * HCC * 128 * 2);
  int* csAll   = (int*)alloc((size_t)3 * NE * 4);

  const int* edges[3] = {e_b, e_sp, e_si};

  // weight pre-split + x pre-split (tiny)
  k_prep<FIN><<<(3 * FIN * 256 + 255) / 256, 256, 0, stream>>>(W1, Wc1);
  k_prep<HCC><<<(3 * HCC * 256 + 255) / 256, 256, 0, stream>>>(W2, Wc2);
  k_split<<<(NN * FIN / 4 + 255) / 256, 256, 0, stream>>>(x, xhi, xlo);

  // CSR build
  hipMemsetAsync(deg3, 0, (size_t)NT3 * 4, stream);
  k_hist3<<<2048, 256, 0, stream>>>(e_b, e_sp, e_si, deg3);
  const int NB = (NT3 + 1023) / 1024;  // 147
  k_bsum<<<NB, 1024, 0, stream>>>(deg3, bsum);
  k_scan2<<<1, 256, 0, stream>>>(bsum, boffs, NB);
  k_rowptr<<<NB, 1024, 0, stream>>>(deg3, boffs, rpA, cursor3);
  for (int r = 0; r < 3; ++r)
    k_scatter<<<1024, 256, 0, stream>>>(edges[r], edges[r] + NE, cursor3 + r * NN,
                                        csAll + (size_t)r * NE, NE);

  const int gblocks = (NN + 63) / 64;   // 782
  const int ablocks = (NN * 64) / 256;  // 12500

  // layer 1
  k_mgemm<FIN><<<dim3(gblocks, 3), 256, 0, stream>>>(
      xhi, xlo, Wc1, a1s, a1d, h3, als3, ald3, NN);
  k_gather3<true><<<ablocks, 256, 0, stream>>>(
      h3, als3, ald3, rpA, csAll, b1, o1hi, o1lo, nullptr, nullptr, nullptr);

  // layer 2 (+ fused final linear)
  k_mgemm<HCC><<<dim3(gblocks, 3), 256, 0, stream>>>(
      o1hi, o1lo, Wc2, a2s, a2d, h3, als3, ald3, NN);
  k_gather3<false><<<ablocks, 256, 0, stream>>>(
      h3, als3, ald3, rpA, csAll, b2, nullptr, nullptr, Wl, bl, out);
}

// Round 10
// 864.682 us; speedup vs baseline: 1.1661x; 1.0269x over previous
//
#include <hip/hip_runtime.h>
#include <hip/hip_bf16.h>
#include <hip/hip_fp16.h>

#define NN 50000
#define NE 800000
#define FIN 128
#define HCC 256   // HEADS*HID
#define OC 64
#define NSL 0.2f
#define NT3 (3 * NN)

typedef __attribute__((ext_vector_type(8))) short sh8;
typedef __attribute__((ext_vector_type(16))) float f32x16;

struct __attribute__((aligned(8))) h4 { __half x, y, z, w; };
struct __attribute__((aligned(8))) s4 { short x, y, z, w; };

__device__ __forceinline__ unsigned short bf_rne(float f) {
  unsigned u = __float_as_uint(f);
  u += 0x7FFF + ((u >> 16) & 1);
  return (unsigned short)(u >> 16);
}

__device__ __forceinline__ float edge_w(float lg) {
  lg = (lg > 0.f) ? lg : NSL * lg;
  return __expf(lg);
}

// -------- weight pre-split into chunked-coalesced layout --------
// W:[3][KK][256] fp32 -> out:[3][cb(2)][hl(2)][KK/8][c(128)][8] bf16
template<int KK>
__global__ __launch_bounds__(256) void k_prep(const float* __restrict__ W,
                                              short* __restrict__ out) {
  int i = blockIdx.x * 256 + threadIdx.x;
  if (i >= 3 * KK * 256) return;
  int r = i / (KK * 256);
  int rem = i - r * KK * 256;
  int k = rem >> 8;
  int n = rem & 255;
  float f = W[i];
  unsigned short hb = bf_rne(f);
  float hf = __uint_as_float(((unsigned)hb) << 16);
  unsigned short lb = bf_rne(f - hf);
  int cb = n >> 7, c = n & 127, ks8 = k >> 3, kj = k & 7;
  size_t base = (size_t)r * 4 * KK * 128;
  size_t oh = base + ((size_t)((cb * 2 + 0) * (KK / 8) + ks8) * 128 + c) * 8 + kj;
  size_t ol = base + ((size_t)((cb * 2 + 1) * (KK / 8) + ks8) * 128 + c) * 8 + kj;
  out[oh] = (short)hb;
  out[ol] = (short)lb;
}

// -------- x fp32 -> bf16 hi/lo --------
__global__ __launch_bounds__(256) void k_split(const float* __restrict__ x,
                                               short* __restrict__ xhi,
                                               short* __restrict__ xlo) {
  int i = blockIdx.x * 256 + threadIdx.x;
  if (i >= NN * FIN / 4) return;
  float4 v = ((const float4*)x)[i];
  s4 h, l;
  float f, hf;
  f = v.x; h.x = (short)bf_rne(f); hf = __uint_as_float(((unsigned)(unsigned short)h.x) << 16); l.x = (short)bf_rne(f - hf);
  f = v.y; h.y = (short)bf_rne(f); hf = __uint_as_float(((unsigned)(unsigned short)h.y) << 16); l.y = (short)bf_rne(f - hf);
  f = v.z; h.z = (short)bf_rne(f); hf = __uint_as_float(((unsigned)(unsigned short)h.z) << 16); l.z = (short)bf_rne(f - hf);
  f = v.w; h.w = (short)bf_rne(f); hf = __uint_as_float(((unsigned)(unsigned short)h.w) << 16); l.w = (short)bf_rne(f - hf);
  ((s4*)xhi)[i] = h;
  ((s4*)xlo)[i] = l;
}

// ---------------- CSR build ----------------
__global__ void k_hist3(const int* __restrict__ e0, const int* __restrict__ e1,
                        const int* __restrict__ e2, int* __restrict__ deg3) {
  int i = blockIdx.x * blockDim.x + threadIdx.x;
  int st = gridDim.x * blockDim.x;
  for (; i < 3 * NE; i += st) {
    int rel = i / NE;
    int j = i - rel * NE;
    const int* e = (rel == 0) ? e0 : ((rel == 1) ? e1 : e2);
    atomicAdd(&deg3[rel * NN + e[NE + j]], 1);
  }
}

__global__ __launch_bounds__(1024) void k_bsum(const int* __restrict__ deg3,
                                               int* __restrict__ bsum) {
  __shared__ int s[1024];
  int t = threadIdx.x;
  int i = blockIdx.x * 1024 + t;
  s[t] = (i < NT3) ? deg3[i] : 0;
  __syncthreads();
  for (int off = 512; off > 0; off >>= 1) {
    if (t < off) s[t] += s[t + off];
    __syncthreads();
  }
  if (t == 0) bsum[blockIdx.x] = s[0];
}

__global__ __launch_bounds__(256) void k_scan2(const int* __restrict__ bsum,
                                               int* __restrict__ boffs, int nb) {
  __shared__ int s[256];
  int t = threadIdx.x;
  int v = (t < nb) ? bsum[t] : 0;
  s[t] = v;
  __syncthreads();
  for (int off = 1; off < 256; off <<= 1) {
    int x = (t >= off) ? s[t - off] : 0;
    __syncthreads();
    s[t] += x;
    __syncthreads();
  }
  if (t < nb) boffs[t] = s[t] - v;  // exclusive
}

__global__ __launch_bounds__(1024) void k_rowptr(const int* __restrict__ deg3,
                                                 const int* __restrict__ boffs,
                                                 int* __restrict__ rpA,
                                                 int* __restrict__ cursor3) {
  __shared__ int s[1024];
  int t = threadIdx.x;
  int i = blockIdx.x * 1024 + t;
  int d = (i < NT3) ? deg3[i] : 0;
  s[t] = d;
  __syncthreads();
  for (int off = 1; off < 1024; off <<= 1) {
    int x = (t >= off) ? s[t - off] : 0;
    __syncthreads();
    s[t] += x;
    __syncthreads();
  }
  if (i < NT3) {
    int excl = boffs[blockIdx.x] + s[t] - d;
    int r = (i < NN) ? 0 : ((i < 2 * NN) ? 1 : 2);
    int n = i - r * NN;
    int val = excl - r * NE;
    rpA[r * (NN + 1) + n] = val;
    cursor3[i] = val;
  }
  if (blockIdx.x == 0 && t < 3) rpA[t * (NN + 1) + NN] = NE;
}

// one relation per launch: random-write region (3.2 MB) stays L2-resident
__global__ void k_scatter(const int* __restrict__ srcv, const int* __restrict__ dstv,
                          int* __restrict__ cursor, int* __restrict__ csr_src, int n) {
  int i = blockIdx.x * blockDim.x + threadIdx.x;
  int st = gridDim.x * blockDim.x;
  for (; i < n; i += st) {
    int pos = atomicAdd(&cursor[dstv[i]], 1);
    csr_src[pos] = srcv[i];
  }
}

// -------- split-bf16 MFMA GEMM (32x32x16), pre-split A, 3 relations, alpha fused ----
// Register-double-buffered K-loop: loads for kst+1 issued before MFMAs of kst.
template<int KK>
__global__ __launch_bounds__(256) void k_mgemm(const short* __restrict__ Ahi,
                                               const short* __restrict__ Alo,
                                               const short* __restrict__ BcAll,
                                               const float* __restrict__ asfAll,
                                               const float* __restrict__ adfAll,
                                               __half* __restrict__ houtAll,
                                               float* __restrict__ alsAll,
                                               float* __restrict__ aldAll, int M) {
  const int rel = blockIdx.y;
  const short* Bc = BcAll + (size_t)rel * 4 * KK * 128;
  const float* asf = asfAll + rel * HCC;
  const float* adf = adfAll + rel * HCC;
  __half* hout = houtAll + (size_t)rel * NN * HCC;
  float* als = alsAll + (size_t)rel * NN * 4;
  float* ald = aldAll + (size_t)rel * NN * 4;

  const int tid = threadIdx.x;
  const int lane = tid & 63;
  const int w = tid >> 6;
  const int l31 = lane & 31;
  const int lg = lane >> 5;
  const int wrow = blockIdx.x * 64 + (w & 1) * 32;
  const int ch = w >> 1;

  f32x16 acc[4];
#pragma unroll
  for (int t = 0; t < 4; ++t) acc[t] = (f32x16)(0.f);

  const int r = wrow + l31;
  const bool aok = r < M;
  const short* ahp = Ahi + (size_t)r * KK;
  const short* alp = Alo + (size_t)r * KK;
  const short* bh = Bc + (size_t)(ch * 2 + 0) * KK * 128 + l31 * 8;
  const short* bl = Bc + (size_t)(ch * 2 + 1) * KK * 128 + l31 * 8;

  const int NK = KK / 16;

#define LOADF(kst, AH, AL, BH, BL)                                     \
  {                                                                    \
    const int k0 = (kst) * 16 + lg * 8;                                \
    AH = (sh8){0, 0, 0, 0, 0, 0, 0, 0};                                \
    AL = AH;                                                           \
    if (aok) {                                                         \
      AH = *(const sh8*)(ahp + k0);                                    \
      AL = *(const sh8*)(alp + k0);                                    \
    }                                                                  \
    const int ks8 = (kst) * 2 + lg;                                    \
    const short* bhp = bh + (size_t)ks8 * 1024;                        \
    const short* blp = bl + (size_t)ks8 * 1024;                        \
    _Pragma("unroll")                                                  \
    for (int t = 0; t < 4; ++t) {                                      \
      BH[t] = *(const sh8*)(bhp + t * 256);                            \
      BL[t] = *(const sh8*)(blp + t * 256);                            \
    }                                                                  \
  }

#define MMBLK(AH, AL, BH, BL)                                                       \
  {                                                                                 \
    _Pragma("unroll")                                                               \
    for (int t = 0; t < 4; ++t) {                                                   \
      acc[t] = __builtin_amdgcn_mfma_f32_32x32x16_bf16(AH, BH[t], acc[t], 0, 0, 0); \
      acc[t] = __builtin_amdgcn_mfma_f32_32x32x16_bf16(AL, BH[t], acc[t], 0, 0, 0); \
      acc[t] = __builtin_amdgcn_mfma_f32_32x32x16_bf16(AH, BL[t], acc[t], 0, 0, 0); \
    }                                                                               \
  }

  sh8 a0h, a0l, b0h[4], b0l[4];
  sh8 a1h, a1l, b1h[4], b1l[4];
  LOADF(0, a0h, a0l, b0h, b0l);
#pragma unroll
  for (int kst = 0; kst < NK - 1; ++kst) {
    if ((kst & 1) == 0) {
      LOADF(kst + 1, a1h, a1l, b1h, b1l);
      MMBLK(a0h, a0l, b0h, b0l);
    } else {
      LOADF(kst + 1, a0h, a0l, b0h, b0l);
      MMBLK(a1h, a1l, b1h, b1l);
    }
  }
  // NK even -> last tile (NK-1) lives in buffer 1
  MMBLK(a1h, a1l, b1h, b1l);
#undef LOADF
#undef MMBLK

  // epilogue: h (fp16) store + fused alpha (2 heads per col-half)
  float asr[4], adr[4];
#pragma unroll
  for (int t = 0; t < 4; ++t) {
    int col = ch * 128 + t * 32 + l31;
    asr[t] = asf[col];
    adr[t] = adf[col];
  }
#pragma unroll
  for (int v = 0; v < 16; ++v) {
    const int rl = (v & 3) + 8 * (v >> 2) + 4 * lg;
    const int row = wrow + rl;
    const bool rok = row < M;
    float s0 = 0.f, s1 = 0.f, d0 = 0.f, d1 = 0.f;
    __half* hp = hout + (size_t)row * 256 + ch * 128 + l31;
#pragma unroll
    for (int t = 0; t < 4; ++t) {
      float dv = acc[t][v];
      if (rok) hp[t * 32] = __float2half(dv);
      if (t < 2) { s0 += dv * asr[t]; d0 += dv * adr[t]; }
      else       { s1 += dv * asr[t]; d1 += dv * adr[t]; }
    }
#pragma unroll
    for (int m = 1; m < 32; m <<= 1) {
      s0 += __shfl_xor(s0, m);
      s1 += __shfl_xor(s1, m);
      d0 += __shfl_xor(d0, m);
      d1 += __shfl_xor(d1, m);
    }
    if (rok && l31 == 0) {
      *(float2*)(als + (size_t)row * 4 + ch * 2) = make_float2(s0, s1);
      *(float2*)(ald + (size_t)row * 4 + ch * 2) = make_float2(d0, d1);
    }
  }
}

// ---------------- fused 3-relation gather core (inline weights, 4-deep) ----------------
template<bool SL>
__device__ __forceinline__ void gat_rel(int n, int head, size_t loff,
                                        const __half* __restrict__ h,
                                        const float* __restrict__ als,
                                        const float* __restrict__ ald,
                                        const int* __restrict__ rp,
                                        const int* __restrict__ cs,
                                        float& ox, float& oy, float& oz, float& ow) {
  float ad = ald[n * 4 + head];
  int rs = rp[n], re = rp[n + 1];
  float ax = 0.f, ay = 0.f, az = 0.f, aw = 0.f, wsum = 0.f;
  int i = rs;
  for (; i + 4 <= re; i += 4) {
    int s0 = cs[i], s1 = cs[i + 1], s2 = cs[i + 2], s3 = cs[i + 3];
    float al0 = als[s0 * 4 + head];
    float al1 = als[s1 * 4 + head];
    float al2 = als[s2 * 4 + head];
    float al3 = als[s3 * 4 + head];
    h4 v0 = *(const h4*)&h[(size_t)s0 * HCC + loff];
    h4 v1 = *(const h4*)&h[(size_t)s1 * HCC + loff];
    h4 v2 = *(const h4*)&h[(size_t)s2 * HCC + loff];
    h4 v3 = *(const h4*)&h[(size_t)s3 * HCC + loff];
    float w0 = edge_w(al0 + ad), w1 = edge_w(al1 + ad);
    float w2 = edge_w(al2 + ad), w3 = edge_w(al3 + ad);
    wsum += (w0 + w1) + (w2 + w3);
    ax = fmaf(w0, __half2float(v0.x), ax); ay = fmaf(w0, __half2float(v0.y), ay);
    az = fmaf(w0, __half2float(v0.z), az); aw = fmaf(w0, __half2float(v0.w), aw);
    ax = fmaf(w1, __half2float(v1.x), ax); ay = fmaf(w1, __half2float(v1.y), ay);
    az = fmaf(w1, __half2float(v1.z), az); aw = fmaf(w1, __half2float(v1.w), aw);
    ax = fmaf(w2, __half2float(v2.x), ax); ay = fmaf(w2, __half2float(v2.y), ay);
    az = fmaf(w2, __half2float(v2.z), az); aw = fmaf(w2, __half2float(v2.w), aw);
    ax = fmaf(w3, __half2float(v3.x), ax); ay = fmaf(w3, __half2float(v3.y), ay);
    az = fmaf(w3, __half2float(v3.z), az); aw = fmaf(w3, __half2float(v3.w), aw);
  }
  for (; i < re; ++i) {
    int s = cs[i];
    float w = edge_w(als[s * 4 + head] + ad);
    wsum += w;
    h4 hv = *(const h4*)&h[(size_t)s * HCC + loff];
    ax = fmaf(w, __half2float(hv.x), ax);
    ay = fmaf(w, __half2float(hv.y), ay);
    az = fmaf(w, __half2float(hv.z), az);
    aw = fmaf(w, __half2float(hv.w), aw);
  }
  if (SL) {
    float w = edge_w(als[n * 4 + head] + ad);
    wsum += w;
    h4 hv = *(const h4*)&h[(size_t)n * HCC + loff];
    ax = fmaf(w, __half2float(hv.x), ax);
    ay = fmaf(w, __half2float(hv.y), ay);
    az = fmaf(w, __half2float(hv.z), az);
    aw = fmaf(w, __half2float(hv.w), aw);
  }
  float inv = 1.0f / (wsum + 1e-16f);
  ox = fmaf(ax, inv, ox);
  oy = fmaf(ay, inv, oy);
  oz = fmaf(az, inv, oz);
  ow = fmaf(aw, inv, ow);
}

// concat layer-1 gather: o1hi/o1lo[n,256] = split-bf16 relu(sum_r gat + sum_r bias)
__global__ __launch_bounds__(256) void k_gather3c(const __half* __restrict__ h3,
                                                  const float* __restrict__ als3,
                                                  const float* __restrict__ ald3,
                                                  const int* __restrict__ rpA,
                                                  const int* __restrict__ csAll,
                                                  const float* __restrict__ bias,
                                                  short* __restrict__ o1hi,
                                                  short* __restrict__ o1lo) {
  int gid = blockIdx.x * blockDim.x + threadIdx.x;
  int n = gid >> 6;
  int lane = threadIdx.x & 63;
  if (n >= NN) return;
  int head = lane >> 4;
  size_t loff = (size_t)lane * 4;
  const size_t HS = (size_t)NN * HCC;
  const size_t AS = (size_t)NN * 4;
  float ox = 0.f, oy = 0.f, oz = 0.f, ow = 0.f;
  gat_rel<false>(n, head, loff, h3,          als3,          ald3,          rpA,                csAll,          ox, oy, oz, ow);
  gat_rel<true >(n, head, loff, h3 + HS,     als3 + AS,     ald3 + AS,     rpA + (NN + 1),     csAll + NE,     ox, oy, oz, ow);
  gat_rel<true >(n, head, loff, h3 + 2 * HS, als3 + 2 * AS, ald3 + 2 * AS, rpA + 2 * (NN + 1), csAll + 2 * NE, ox, oy, oz, ow);
  float4 b0 = *(const float4*)&bias[lane * 4];
  float4 b1 = *(const float4*)&bias[HCC + lane * 4];
  float4 b2 = *(const float4*)&bias[2 * HCC + lane * 4];
  float vv[4];
  vv[0] = fmaxf(ox + b0.x + b1.x + b2.x, 0.f);
  vv[1] = fmaxf(oy + b0.y + b1.y + b2.y, 0.f);
  vv[2] = fmaxf(oz + b0.z + b1.z + b2.z, 0.f);
  vv[3] = fmaxf(ow + b0.w + b1.w + b2.w, 0.f);
  s4 hv, lv;
  short* hp = (short*)&hv;
  short* lp = (short*)&lv;
#pragma unroll
  for (int j = 0; j < 4; ++j) {
    unsigned short hb = bf_rne(vv[j]);
    float hf = __uint_as_float(((unsigned)hb) << 16);
    hp[j] = (short)hb;
    lp[j] = (short)bf_rne(vv[j] - hf);
  }
  *(s4*)&o1hi[(size_t)n * HCC + loff] = hv;
  *(s4*)&o1lo[(size_t)n * HCC + loff] = lv;
}

// layer-2 gather + fused final: outp[n,64] = relu(mean + biases) @ Wl + bl
__global__ __launch_bounds__(256) void k_gather3f(const __half* __restrict__ h3,
                                                  const float* __restrict__ als3,
                                                  const float* __restrict__ ald3,
                                                  const int* __restrict__ rpA,
                                                  const int* __restrict__ csAll,
                                                  const float* __restrict__ bias,
                                                  const float* __restrict__ Wl,
                                                  const float* __restrict__ bl,
                                                  float* __restrict__ outp) {
  __shared__ float Ws[64 * 64];
  for (int i = threadIdx.x; i < 4096; i += 256) Ws[i] = Wl[i];
  __syncthreads();  // safe: grid covers exactly NN*64 threads
  int gid = blockIdx.x * blockDim.x + threadIdx.x;
  int n = gid >> 6;
  int lane = threadIdx.x & 63;
  if (n >= NN) return;
  int head = lane >> 4;
  size_t loff = (size_t)lane * 4;
  const size_t HS = (size_t)NN * HCC;
  const size_t AS = (size_t)NN * 4;
  float ox = 0.f, oy = 0.f, oz = 0.f, ow = 0.f;
  gat_rel<false>(n, head, loff, h3,          als3,          ald3,          rpA,                csAll,          ox, oy, oz, ow);
  gat_rel<true >(n, head, loff, h3 + HS,     als3 + AS,     ald3 + AS,     rpA + (NN + 1),     csAll + NE,     ox, oy, oz, ow);
  gat_rel<true >(n, head, loff, h3 + 2 * HS, als3 + 2 * AS, ald3 + 2 * AS, rpA + 2 * (NN + 1), csAll + 2 * NE, ox, oy, oz, ow);
  // butterfly: every lane ends with 4-head sums for within-head ch 4*(lane&15)+j
  ox += __shfl_xor(ox, 16); oy += __shfl_xor(oy, 16);
  oz += __shfl_xor(oz, 16); ow += __shfl_xor(ow, 16);
  ox += __shfl_xor(ox, 32); oy += __shfl_xor(oy, 32);
  oz += __shfl_xor(oz, 32); ow += __shfl_xor(ow, 32);
  int q0 = lane & 15;
  float4 b0 = *(const float4*)&bias[q0 * 4];
  float4 b1 = *(const float4*)&bias[OC + q0 * 4];
  float4 b2 = *(const float4*)&bias[2 * OC + q0 * 4];
  float x0 = fmaxf(0.25f * ox + b0.x + b1.x + b2.x, 0.f);
  float x1 = fmaxf(0.25f * oy + b0.y + b1.y + b2.y, 0.f);
  float x2 = fmaxf(0.25f * oz + b0.z + b1.z + b2.z, 0.f);
  float x3 = fmaxf(0.25f * ow + b0.w + b1.w + b2.w, 0.f);
  float acc = bl[lane];
#pragma unroll
  for (int q = 0; q < 16; ++q) {
    float xa = __shfl(x0, q);
    float xb = __shfl(x1, q);
    float xc = __shfl(x2, q);
    float xd = __shfl(x3, q);
    acc = fmaf(xa, Ws[(4 * q + 0) * 64 + lane], acc);
    acc = fmaf(xb, Ws[(4 * q + 1) * 64 + lane], acc);
    acc = fmaf(xc, Ws[(4 * q + 2) * 64 + lane], acc);
    acc = fmaf(xd, Ws[(4 * q + 3) * 64 + lane], acc);
  }
  outp[(size_t)n * OC + lane] = acc;
}

extern "C" void kernel_launch(void* const* d_in, const int* in_sizes, int n_in,
                              void* d_out, int out_size, void* d_ws, size_t ws_size,
                              hipStream_t stream) {
  const float* x   = (const float*)d_in[0];
  const int* e_b   = (const int*)d_in[1];
  const int* e_sp  = (const int*)d_in[2];
  const int* e_si  = (const int*)d_in[3];
  const float* W1  = (const float*)d_in[4];
  const float* a1s = (const float*)d_in[5];
  const float* a1d = (const float*)d_in[6];
  const float* b1  = (const float*)d_in[7];
  const float* W2  = (const float*)d_in[8];
  const float* a2s = (const float*)d_in[9];
  const float* a2d = (const float*)d_in[10];
  const float* b2  = (const float*)d_in[11];
  const float* Wl  = (const float*)d_in[12];
  const float* bl  = (const float*)d_in[13];
  float* out = (float*)d_out;

  char* ws = (char*)d_ws;
  size_t off = 0;
  auto alloc = [&](size_t b) {
    char* p = ws + off;
    off += (b + 255) & ~(size_t)255;
    return p;
  };
  __half* h3  = (__half*)alloc((size_t)3 * NN * HCC * 2);   // 76.8 MB
  short* o1hi = (short*)alloc((size_t)NN * HCC * 2);        // 25.6 MB
  short* o1lo = (short*)alloc((size_t)NN * HCC * 2);        // 25.6 MB
  short* xhi  = (short*)alloc((size_t)NN * FIN * 2);        // 12.8 MB
  short* xlo  = (short*)alloc((size_t)NN * FIN * 2);        // 12.8 MB
  float* als3 = (float*)alloc((size_t)3 * NN * 4 * 4);
  float* ald3 = (float*)alloc((size_t)3 * NN * 4 * 4);
  int* deg3    = (int*)alloc((size_t)NT3 * 4);
  int* cursor3 = (int*)alloc((size_t)NT3 * 4);
  int* rpA     = (int*)alloc((size_t)3 * (NN + 1) * 4);
  int* bsum    = (int*)alloc(256 * 4);
  int* boffs   = (int*)alloc(256 * 4);
  short* Wc1   = (short*)alloc((size_t)3 * 4 * FIN * 128 * 2);
  short* Wc2   = (short*)alloc((size_t)3 * 4 * HCC * 128 * 2);
  int* csAll   = (int*)alloc((size_t)3 * NE * 4);

  const int* edges[3] = {e_b, e_sp, e_si};

  // weight pre-split + x pre-split (tiny)
  k_prep<FIN><<<(3 * FIN * 256 + 255) / 256, 256, 0, stream>>>(W1, Wc1);
  k_prep<HCC><<<(3 * HCC * 256 + 255) / 256, 256, 0, stream>>>(W2, Wc2);
  k_split<<<(NN * FIN / 4 + 255) / 256, 256, 0, stream>>>(x, xhi, xlo);

  // CSR build
  hipMemsetAsync(deg3, 0, (size_t)NT3 * 4, stream);
  k_hist3<<<2048, 256, 0, stream>>>(e_b, e_sp, e_si, deg3);
  const int NB = (NT3 + 1023) / 1024;  // 147
  k_bsum<<<NB, 1024, 0, stream>>>(deg3, bsum);
  k_scan2<<<1, 256, 0, stream>>>(bsum, boffs, NB);
  k_rowptr<<<NB, 1024, 0, stream>>>(deg3, boffs, rpA, cursor3);
  for (int r = 0; r < 3; ++r)
    k_scatter<<<1024, 256, 0, stream>>>(edges[r], edges[r] + NE, cursor3 + r * NN,
                                        csAll + (size_t)r * NE, NE);

  const int gblocks = (NN + 63) / 64;   // 782
  const int ablocks = (NN * 64) / 256;  // 12500

  // layer 1
  k_mgemm<FIN><<<dim3(gblocks, 3), 256, 0, stream>>>(
      xhi, xlo, Wc1, a1s, a1d, h3, als3, ald3, NN);
  k_gather3c<<<ablocks, 256, 0, stream>>>(
      h3, als3, ald3, rpA, csAll, b1, o1hi, o1lo);

  // layer 2 (+ fused final linear)
  k_mgemm<HCC><<<dim3(gblocks, 3), 256, 0, stream>>>(
      o1hi, o1lo, Wc2, a2s, a2d, h3, als3, ald3, NN);
  k_gather3f<<<ablocks, 256, 0, stream>>>(
      h3, als3, ald3, rpA, csAll, b2, Wl, bl, out);
}

// Round 11
// 861.095 us; speedup vs baseline: 1.1710x; 1.0042x over previous
//
#include <hip/hip_runtime.h>
#include <hip/hip_bf16.h>
#include <hip/hip_fp16.h>

#define NN 50000
#define NE 800000
#define FIN 128
#define HCC 256   // HEADS*HID
#define OC 64
#define NSL 0.2f
#define NT3 (3 * NN)

typedef __attribute__((ext_vector_type(8))) short sh8;
typedef __attribute__((ext_vector_type(16))) float f32x16;

struct __attribute__((aligned(8))) h4 { __half x, y, z, w; };
struct __attribute__((aligned(8))) s4 { short x, y, z, w; };

typedef const __attribute__((address_space(1))) unsigned int* gas_t;
typedef __attribute__((address_space(3))) unsigned int* las_t;

__device__ __forceinline__ unsigned short bf_rne(float f) {
  unsigned u = __float_as_uint(f);
  u += 0x7FFF + ((u >> 16) & 1);
  return (unsigned short)(u >> 16);
}

__device__ __forceinline__ float edge_w(float lg) {
  lg = (lg > 0.f) ? lg : NSL * lg;
  return __expf(lg);
}

// -------- weight pre-split into per-K-step contiguous chunks --------
// W:[3][KK][256] fp32 -> out:[3][kst][q(8)][c(128)][kj(8)] bf16
// q = (cb*2 + hl)*2 + p, kst=k/16, p=(k/8)&1, kj=k&7, cb=n/128, c=n&127.
// Each kst block = 8 chunks x 1024 shorts = 16 KB, contiguous.
template<int KK>
__global__ __launch_bounds__(256) void k_prep(const float* __restrict__ W,
                                              short* __restrict__ out) {
  int i = blockIdx.x * 256 + threadIdx.x;
  if (i >= 3 * KK * 256) return;
  int r = i / (KK * 256);
  int rem = i - r * KK * 256;
  int k = rem >> 8;
  int n = rem & 255;
  float f = W[i];
  unsigned short hb = bf_rne(f);
  float hf = __uint_as_float(((unsigned)hb) << 16);
  unsigned short lb = bf_rne(f - hf);
  int cb = n >> 7, c = n & 127;
  int kst = k >> 4, p = (k >> 3) & 1, kj = k & 7;
  size_t base = (size_t)r * 4 * KK * 128;
  size_t oh = base + ((size_t)(kst * 8 + (cb * 2 + 0) * 2 + p) * 128 + c) * 8 + kj;
  size_t ol = base + ((size_t)(kst * 8 + (cb * 2 + 1) * 2 + p) * 128 + c) * 8 + kj;
  out[oh] = (short)hb;
  out[ol] = (short)lb;
}

// -------- x fp32 -> bf16 hi/lo --------
__global__ __launch_bounds__(256) void k_split(const float* __restrict__ x,
                                               short* __restrict__ xhi,
                                               short* __restrict__ xlo) {
  int i = blockIdx.x * 256 + threadIdx.x;
  if (i >= NN * FIN / 4) return;
  float4 v = ((const float4*)x)[i];
  s4 h, l;
  float f, hf;
  f = v.x; h.x = (short)bf_rne(f); hf = __uint_as_float(((unsigned)(unsigned short)h.x) << 16); l.x = (short)bf_rne(f - hf);
  f = v.y; h.y = (short)bf_rne(f); hf = __uint_as_float(((unsigned)(unsigned short)h.y) << 16); l.y = (short)bf_rne(f - hf);
  f = v.z; h.z = (short)bf_rne(f); hf = __uint_as_float(((unsigned)(unsigned short)h.z) << 16); l.z = (short)bf_rne(f - hf);
  f = v.w; h.w = (short)bf_rne(f); hf = __uint_as_float(((unsigned)(unsigned short)h.w) << 16); l.w = (short)bf_rne(f - hf);
  ((s4*)xhi)[i] = h;
  ((s4*)xlo)[i] = l;
}

// ---------------- CSR build ----------------
__global__ void k_hist3(const int* __restrict__ e0, const int* __restrict__ e1,
                        const int* __restrict__ e2, int* __restrict__ deg3) {
  int i = blockIdx.x * blockDim.x + threadIdx.x;
  int st = gridDim.x * blockDim.x;
  for (; i < 3 * NE; i += st) {
    int rel = i / NE;
    int j = i - rel * NE;
    const int* e = (rel == 0) ? e0 : ((rel == 1) ? e1 : e2);
    atomicAdd(&deg3[rel * NN + e[NE + j]], 1);
  }
}

__global__ __launch_bounds__(1024) void k_bsum(const int* __restrict__ deg3,
                                               int* __restrict__ bsum) {
  __shared__ int s[1024];
  int t = threadIdx.x;
  int i = blockIdx.x * 1024 + t;
  s[t] = (i < NT3) ? deg3[i] : 0;
  __syncthreads();
  for (int off = 512; off > 0; off >>= 1) {
    if (t < off) s[t] += s[t + off];
    __syncthreads();
  }
  if (t == 0) bsum[blockIdx.x] = s[0];
}

__global__ __launch_bounds__(256) void k_scan2(const int* __restrict__ bsum,
                                               int* __restrict__ boffs, int nb) {
  __shared__ int s[256];
  int t = threadIdx.x;
  int v = (t < nb) ? bsum[t] : 0;
  s[t] = v;
  __syncthreads();
  for (int off = 1; off < 256; off <<= 1) {
    int x = (t >= off) ? s[t - off] : 0;
    __syncthreads();
    s[t] += x;
    __syncthreads();
  }
  if (t < nb) boffs[t] = s[t] - v;  // exclusive
}

__global__ __launch_bounds__(1024) void k_rowptr(const int* __restrict__ deg3,
                                                 const int* __restrict__ boffs,
                                                 int* __restrict__ rpA,
                                                 int* __restrict__ cursor3) {
  __shared__ int s[1024];
  int t = threadIdx.x;
  int i = blockIdx.x * 1024 + t;
  int d = (i < NT3) ? deg3[i] : 0;
  s[t] = d;
  __syncthreads();
  for (int off = 1; off < 1024; off <<= 1) {
    int x = (t >= off) ? s[t - off] : 0;
    __syncthreads();
    s[t] += x;
    __syncthreads();
  }
  if (i < NT3) {
    int excl = boffs[blockIdx.x] + s[t] - d;
    int r = (i < NN) ? 0 : ((i < 2 * NN) ? 1 : 2);
    int n = i - r * NN;
    int val = excl - r * NE;
    rpA[r * (NN + 1) + n] = val;
    cursor3[i] = val;
  }
  if (blockIdx.x == 0 && t < 3) rpA[t * (NN + 1) + NN] = NE;
}

// one relation per launch: random-write region (3.2 MB) stays L2-resident
__global__ void k_scatter(const int* __restrict__ srcv, const int* __restrict__ dstv,
                          int* __restrict__ cursor, int* __restrict__ csr_src, int n) {
  int i = blockIdx.x * blockDim.x + threadIdx.x;
  int st = gridDim.x * blockDim.x;
  for (; i < n; i += st) {
    int pos = atomicAdd(&cursor[dstv[i]], 1);
    csr_src[pos] = srcv[i];
  }
}

// -------- split-bf16 MFMA GEMM (32x32x16), LDS-staged B, pre-split A --------
// B staged per K-step (16 KB contiguous) via global_load_lds, double-buffered.
// A register ping-pong (issued one step ahead). One barrier per K-step.
template<int KK>
__global__ __launch_bounds__(256) void k_mgemm(const short* __restrict__ Ahi,
                                               const short* __restrict__ Alo,
                                               const short* __restrict__ BcAll,
                                               const float* __restrict__ asfAll,
                                               const float* __restrict__ adfAll,
                                               __half* __restrict__ houtAll,
                                               float* __restrict__ alsAll,
                                               float* __restrict__ aldAll, int M) {
  __shared__ short Bs[2][8192];  // 2 x 16 KB
  const int rel = blockIdx.y;
  const short* Brel = BcAll + (size_t)rel * 4 * KK * 128;
  const float* asf = asfAll + rel * HCC;
  const float* adf = adfAll + rel * HCC;
  __half* hout = houtAll + (size_t)rel * NN * HCC;
  float* als = alsAll + (size_t)rel * NN * 4;
  float* ald = aldAll + (size_t)rel * NN * 4;

  const int tid = threadIdx.x;
  const int lane = tid & 63;
  const int w = tid >> 6;
  const int l31 = lane & 31;
  const int lg = lane >> 5;
  const int wrow = blockIdx.x * 64 + (w & 1) * 32;
  const int ch = w >> 1;

  f32x16 acc[4];
#pragma unroll
  for (int t = 0; t < 4; ++t) acc[t] = (f32x16)(0.f);

  const int r = wrow + l31;
  const bool aok = r < M;
  const short* ahp = Ahi + (size_t)r * KK;
  const short* alp = Alo + (size_t)r * KK;
  const int qh = (ch * 2 + 0) * 2 + lg;  // hi chunk for this wave
  const int ql = (ch * 2 + 1) * 2 + lg;  // lo chunk

  const int NK = KK / 16;

#define STAGE(kst, buf)                                                      \
  {                                                                          \
    _Pragma("unroll")                                                        \
    for (int it = 0; it < 4; ++it) {                                         \
      int so = it * 2048 + w * 512;                                          \
      __builtin_amdgcn_global_load_lds(                                      \
          (gas_t)(const void*)(Brel + (size_t)(kst) * 8192 + so + lane * 8), \
          (las_t)(void*)&Bs[buf][so], 16, 0, 0);                             \
    }                                                                        \
  }

#define LOADA(kst, AH, AL)                 \
  {                                        \
    const int k0 = (kst) * 16 + lg * 8;    \
    AH = (sh8){0, 0, 0, 0, 0, 0, 0, 0};    \
    AL = AH;                               \
    if (aok) {                             \
      AH = *(const sh8*)(ahp + k0);        \
      AL = *(const sh8*)(alp + k0);        \
    }                                      \
  }

#define MMBLK(buf, AH, AL)                                                            \
  {                                                                                   \
    _Pragma("unroll")                                                                 \
    for (int t = 0; t < 4; ++t) {                                                     \
      sh8 bhf = *(const sh8*)&Bs[buf][(size_t)(qh * 128 + t * 32 + l31) * 8];         \
      sh8 blf = *(const sh8*)&Bs[buf][(size_t)(ql * 128 + t * 32 + l31) * 8];         \
      acc[t] = __builtin_amdgcn_mfma_f32_32x32x16_bf16(AH, bhf, acc[t], 0, 0, 0);     \
      acc[t] = __builtin_amdgcn_mfma_f32_32x32x16_bf16(AL, bhf, acc[t], 0, 0, 0);     \
      acc[t] = __builtin_amdgcn_mfma_f32_32x32x16_bf16(AH, blf, acc[t], 0, 0, 0);     \
    }                                                                                 \
  }

  sh8 a0h, a0l, a1h, a1l;
  LOADA(0, a0h, a0l);
  STAGE(0, 0);
#pragma unroll
  for (int kst = 0; kst < NK; ++kst) {
    __syncthreads();  // Bs[kst&1] staged; prior reads of other buffer drained
    if (kst + 1 < NK) {
      STAGE(kst + 1, (kst & 1) ^ 1);
      if ((kst & 1) == 0) { LOADA(kst + 1, a1h, a1l); }
      else                { LOADA(kst + 1, a0h, a0l); }
    }
    if ((kst & 1) == 0) { MMBLK(0, a0h, a0l); }
    else                { MMBLK(1, a1h, a1l); }
  }
#undef STAGE
#undef LOADA
#undef MMBLK

  // epilogue: h (fp16) store + fused alpha (2 heads per col-half)
  float asr[4], adr[4];
#pragma unroll
  for (int t = 0; t < 4; ++t) {
    int col = ch * 128 + t * 32 + l31;
    asr[t] = asf[col];
    adr[t] = adf[col];
  }
#pragma unroll
  for (int v = 0; v < 16; ++v) {
    const int rl = (v & 3) + 8 * (v >> 2) + 4 * lg;
    const int row = wrow + rl;
    const bool rok = row < M;
    float s0 = 0.f, s1 = 0.f, d0 = 0.f, d1 = 0.f;
    __half* hp = hout + (size_t)row * 256 + ch * 128 + l31;
#pragma unroll
    for (int t = 0; t < 4; ++t) {
      float dv = acc[t][v];
      if (rok) hp[t * 32] = __float2half(dv);
      if (t < 2) { s0 += dv * asr[t]; d0 += dv * adr[t]; }
      else       { s1 += dv * asr[t]; d1 += dv * adr[t]; }
    }
#pragma unroll
    for (int m = 1; m < 32; m <<= 1) {
      s0 += __shfl_xor(s0, m);
      s1 += __shfl_xor(s1, m);
      d0 += __shfl_xor(d0, m);
      d1 += __shfl_xor(d1, m);
    }
    if (rok && l31 == 0) {
      *(float2*)(als + (size_t)row * 4 + ch * 2) = make_float2(s0, s1);
      *(float2*)(ald + (size_t)row * 4 + ch * 2) = make_float2(d0, d1);
    }
  }
}

// ---------------- fused 3-relation gather core (inline weights, 4-deep) ----------------
template<bool SL>
__device__ __forceinline__ void gat_rel(int n, int head, size_t loff,
                                        const __half* __restrict__ h,
                                        const float* __restrict__ als,
                                        const float* __restrict__ ald,
                                        const int* __restrict__ rp,
                                        const int* __restrict__ cs,
                                        float& ox, float& oy, float& oz, float& ow) {
  float ad = ald[n * 4 + head];
  int rs = rp[n], re = rp[n + 1];
  float ax = 0.f, ay = 0.f, az = 0.f, aw = 0.f, wsum = 0.f;
  int i = rs;
  for (; i + 4 <= re; i += 4) {
    int s0 = cs[i], s1 = cs[i + 1], s2 = cs[i + 2], s3 = cs[i + 3];
    float al0 = als[s0 * 4 + head];
    float al1 = als[s1 * 4 + head];
    float al2 = als[s2 * 4 + head];
    float al3 = als[s3 * 4 + head];
    h4 v0 = *(const h4*)&h[(size_t)s0 * HCC + loff];
    h4 v1 = *(const h4*)&h[(size_t)s1 * HCC + loff];
    h4 v2 = *(const h4*)&h[(size_t)s2 * HCC + loff];
    h4 v3 = *(const h4*)&h[(size_t)s3 * HCC + loff];
    float w0 = edge_w(al0 + ad), w1 = edge_w(al1 + ad);
    float w2 = edge_w(al2 + ad), w3 = edge_w(al3 + ad);
    wsum += (w0 + w1) + (w2 + w3);
    ax = fmaf(w0, __half2float(v0.x), ax); ay = fmaf(w0, __half2float(v0.y), ay);
    az = fmaf(w0, __half2float(v0.z), az); aw = fmaf(w0, __half2float(v0.w), aw);
    ax = fmaf(w1, __half2float(v1.x), ax); ay = fmaf(w1, __half2float(v1.y), ay);
    az = fmaf(w1, __half2float(v1.z), az); aw = fmaf(w1, __half2float(v1.w), aw);
    ax = fmaf(w2, __half2float(v2.x), ax); ay = fmaf(w2, __half2float(v2.y), ay);
    az = fmaf(w2, __half2float(v2.z), az); aw = fmaf(w2, __half2float(v2.w), aw);
    ax = fmaf(w3, __half2float(v3.x), ax); ay = fmaf(w3, __half2float(v3.y), ay);
    az = fmaf(w3, __half2float(v3.z), az); aw = fmaf(w3, __half2float(v3.w), aw);
  }
  for (; i < re; ++i) {
    int s = cs[i];
    float w = edge_w(als[s * 4 + head] + ad);
    wsum += w;
    h4 hv = *(const h4*)&h[(size_t)s * HCC + loff];
    ax = fmaf(w, __half2float(hv.x), ax);
    ay = fmaf(w, __half2float(hv.y), ay);
    az = fmaf(w, __half2float(hv.z), az);
    aw = fmaf(w, __half2float(hv.w), aw);
  }
  if (SL) {
    float w = edge_w(als[n * 4 + head] + ad);
    wsum += w;
    h4 hv = *(const h4*)&h[(size_t)n * HCC + loff];
    ax = fmaf(w, __half2float(hv.x), ax);
    ay = fmaf(w, __half2float(hv.y), ay);
    az = fmaf(w, __half2float(hv.z), az);
    aw = fmaf(w, __half2float(hv.w), aw);
  }
  float inv = 1.0f / (wsum + 1e-16f);
  ox = fmaf(ax, inv, ox);
  oy = fmaf(ay, inv, oy);
  oz = fmaf(az, inv, oz);
  ow = fmaf(aw, inv, ow);
}

// concat layer-1 gather: o1hi/o1lo[n,256] = split-bf16 relu(sum_r gat + sum_r bias)
__global__ __launch_bounds__(256) void k_gather3c(const __half* __restrict__ h3,
                                                  const float* __restrict__ als3,
                                                  const float* __restrict__ ald3,
                                                  const int* __restrict__ rpA,
                                                  const int* __restrict__ csAll,
                                                  const float* __restrict__ bias,
                                                  short* __restrict__ o1hi,
                                                  short* __restrict__ o1lo) {
  int gid = blockIdx.x * blockDim.x + threadIdx.x;
  int n = gid >> 6;
  int lane = threadIdx.x & 63;
  if (n >= NN) return;
  int head = lane >> 4;
  size_t loff = (size_t)lane * 4;
  const size_t HS = (size_t)NN * HCC;
  const size_t AS = (size_t)NN * 4;
  float ox = 0.f, oy = 0.f, oz = 0.f, ow = 0.f;
  gat_rel<false>(n, head, loff, h3,          als3,          ald3,          rpA,                csAll,          ox, oy, oz, ow);
  gat_rel<true >(n, head, loff, h3 + HS,     als3 + AS,     ald3 + AS,     rpA + (NN + 1),     csAll + NE,     ox, oy, oz, ow);
  gat_rel<true >(n, head, loff, h3 + 2 * HS, als3 + 2 * AS, ald3 + 2 * AS, rpA + 2 * (NN + 1), csAll + 2 * NE, ox, oy, oz, ow);
  float4 b0 = *(const float4*)&bias[lane * 4];
  float4 b1 = *(const float4*)&bias[HCC + lane * 4];
  float4 b2 = *(const float4*)&bias[2 * HCC + lane * 4];
  float vv[4];
  vv[0] = fmaxf(ox + b0.x + b1.x + b2.x, 0.f);
  vv[1] = fmaxf(oy + b0.y + b1.y + b2.y, 0.f);
  vv[2] = fmaxf(oz + b0.z + b1.z + b2.z, 0.f);
  vv[3] = fmaxf(ow + b0.w + b1.w + b2.w, 0.f);
  s4 hv, lv;
  short* hp = (short*)&hv;
  short* lp = (short*)&lv;
#pragma unroll
  for (int j = 0; j < 4; ++j) {
    unsigned short hb = bf_rne(vv[j]);
    float hf = __uint_as_float(((unsigned)hb) << 16);
    hp[j] = (short)hb;
    lp[j] = (short)bf_rne(vv[j] - hf);
  }
  *(s4*)&o1hi[(size_t)n * HCC + loff] = hv;
  *(s4*)&o1lo[(size_t)n * HCC + loff] = lv;
}

// layer-2 gather + fused final: outp[n,64] = relu(mean + biases) @ Wl + bl
__global__ __launch_bounds__(256) void k_gather3f(const __half* __restrict__ h3,
                                                  const float* __restrict__ als3,
                                                  const float* __restrict__ ald3,
                                                  const int* __restrict__ rpA,
                                                  const int* __restrict__ csAll,
                                                  const float* __restrict__ bias,
                                                  const float* __restrict__ Wl,
                                                  const float* __restrict__ bl,
                                                  float* __restrict__ outp) {
  __shared__ float Ws[64 * 64];
  for (int i = threadIdx.x; i < 4096; i += 256) Ws[i] = Wl[i];
  __syncthreads();  // safe: grid covers exactly NN*64 threads
  int gid = blockIdx.x * blockDim.x + threadIdx.x;
  int n = gid >> 6;
  int lane = threadIdx.x & 63;
  if (n >= NN) return;
  int head = lane >> 4;
  size_t loff = (size_t)lane * 4;
  const size_t HS = (size_t)NN * HCC;
  const size_t AS = (size_t)NN * 4;
  float ox = 0.f, oy = 0.f, oz = 0.f, ow = 0.f;
  gat_rel<false>(n, head, loff, h3,          als3,          ald3,          rpA,                csAll,          ox, oy, oz, ow);
  gat_rel<true >(n, head, loff, h3 + HS,     als3 + AS,     ald3 + AS,     rpA + (NN + 1),     csAll + NE,     ox, oy, oz, ow);
  gat_rel<true >(n, head, loff, h3 + 2 * HS, als3 + 2 * AS, ald3 + 2 * AS, rpA + 2 * (NN + 1), csAll + 2 * NE, ox, oy, oz, ow);
  // butterfly: every lane ends with 4-head sums for within-head ch 4*(lane&15)+j
  ox += __shfl_xor(ox, 16); oy += __shfl_xor(oy, 16);
  oz += __shfl_xor(oz, 16); ow += __shfl_xor(ow, 16);
  ox += __shfl_xor(ox, 32); oy += __shfl_xor(oy, 32);
  oz += __shfl_xor(oz, 32); ow += __shfl_xor(ow, 32);
  int q0 = lane & 15;
  float4 b0 = *(const float4*)&bias[q0 * 4];
  float4 b1 = *(const float4*)&bias[OC + q0 * 4];
  float4 b2 = *(const float4*)&bias[2 * OC + q0 * 4];
  float x0 = fmaxf(0.25f * ox + b0.x + b1.x + b2.x, 0.f);
  float x1 = fmaxf(0.25f * oy + b0.y + b1.y + b2.y, 0.f);
  float x2 = fmaxf(0.25f * oz + b0.z + b1.z + b2.z, 0.f);
  float x3 = fmaxf(0.25f * ow + b0.w + b1.w + b2.w, 0.f);
  float acc = bl[lane];
#pragma unroll
  for (int q = 0; q < 16; ++q) {
    float xa = __shfl(x0, q);
    float xb = __shfl(x1, q);
    float xc = __shfl(x2, q);
    float xd = __shfl(x3, q);
    acc = fmaf(xa, Ws[(4 * q + 0) * 64 + lane], acc);
    acc = fmaf(xb, Ws[(4 * q + 1) * 64 + lane], acc);
    acc = fmaf(xc, Ws[(4 * q + 2) * 64 + lane], acc);
    acc = fmaf(xd, Ws[(4 * q + 3) * 64 + lane], acc);
  }
  outp[(size_t)n * OC + lane] = acc;
}

extern "C" void kernel_launch(void* const* d_in, const int* in_sizes, int n_in,
                              void* d_out, int out_size, void* d_ws, size_t ws_size,
                              hipStream_t stream) {
  const float* x   = (const float*)d_in[0];
  const int* e_b   = (const int*)d_in[1];
  const int* e_sp  = (const int*)d_in[2];
  const int* e_si  = (const int*)d_in[3];
  const float* W1  = (const float*)d_in[4];
  const float* a1s = (const float*)d_in[5];
  const float* a1d = (const float*)d_in[6];
  const float* b1  = (const float*)d_in[7];
  const float* W2  = (const float*)d_in[8];
  const float* a2s = (const float*)d_in[9];
  const float* a2d = (const float*)d_in[10];
  const float* b2  = (const float*)d_in[11];
  const float* Wl  = (const float*)d_in[12];
  const float* bl  = (const float*)d_in[13];
  float* out = (float*)d_out;

  char* ws = (char*)d_ws;
  size_t off = 0;
  auto alloc = [&](size_t b) {
    char* p = ws + off;
    off += (b + 255) & ~(size_t)255;
    return p;
  };
  __half* h3  = (__half*)alloc((size_t)3 * NN * HCC * 2);   // 76.8 MB
  short* o1hi = (short*)alloc((size_t)NN * HCC * 2);        // 25.6 MB
  short* o1lo = (short*)alloc((size_t)NN * HCC * 2);        // 25.6 MB
  short* xhi  = (short*)alloc((size_t)NN * FIN * 2);        // 12.8 MB
  short* xlo  = (short*)alloc((size_t)NN * FIN * 2);        // 12.8 MB
  float* als3 = (float*)alloc((size_t)3 * NN * 4 * 4);
  float* ald3 = (float*)alloc((size_t)3 * NN * 4 * 4);
  int* deg3    = (int*)alloc((size_t)NT3 * 4);
  int* cursor3 = (int*)alloc((size_t)NT3 * 4);
  int* rpA     = (int*)alloc((size_t)3 * (NN + 1) * 4);
  int* bsum    = (int*)alloc(256 * 4);
  int* boffs   = (int*)alloc(256 * 4);
  short* Wc1   = (short*)alloc((size_t)3 * 4 * FIN * 128 * 2);
  short* Wc2   = (short*)alloc((size_t)3 * 4 * HCC * 128 * 2);
  int* csAll   = (int*)alloc((size_t)3 * NE * 4);

  const int* edges[3] = {e_b, e_sp, e_si};

  // weight pre-split + x pre-split (tiny)
  k_prep<FIN><<<(3 * FIN * 256 + 255) / 256, 256, 0, stream>>>(W1, Wc1);
  k_prep<HCC><<<(3 * HCC * 256 + 255) / 256, 256, 0, stream>>>(W2, Wc2);
  k_split<<<(NN * FIN / 4 + 255) / 256, 256, 0, stream>>>(x, xhi, xlo);

  // CSR build
  hipMemsetAsync(deg3, 0, (size_t)NT3 * 4, stream);
  k_hist3<<<2048, 256, 0, stream>>>(e_b, e_sp, e_si, deg3);
  const int NB = (NT3 + 1023) / 1024;  // 147
  k_bsum<<<NB, 1024, 0, stream>>>(deg3, bsum);
  k_scan2<<<1, 256, 0, stream>>>(bsum, boffs, NB);
  k_rowptr<<<NB, 1024, 0, stream>>>(deg3, boffs, rpA, cursor3);
  for (int r = 0; r < 3; ++r)
    k_scatter<<<1024, 256, 0, stream>>>(edges[r], edges[r] + NE, cursor3 + r * NN,
                                        csAll + (size_t)r * NE, NE);

  const int gblocks = (NN + 63) / 64;   // 782
  const int ablocks = (NN * 64) / 256;  // 12500

  // layer 1
  k_mgemm<FIN><<<dim3(gblocks, 3), 256, 0, stream>>>(
      xhi, xlo, Wc1, a1s, a1d, h3, als3, ald3, NN);
  k_gather3c<<<ablocks, 256, 0, stream>>>(
      h3, als3, ald3, rpA, csAll, b1, o1hi, o1lo);

  // layer 2 (+ fused final linear)
  k_mgemm<HCC><<<dim3(gblocks, 3), 256, 0, stream>>>(
      o1hi, o1lo, Wc2, a2s, a2d, h3, als3, ald3, NN);
  k_gather3f<<<ablocks, 256, 0, stream>>>(
      h3, als3, ald3, rpA, csAll, b2, Wl, bl, out);
}